// Round 4
// baseline (139.079 us; speedup 1.0000x reference)
//
#include <hip/hip_runtime.h>
#include <hip/hip_bf16.h>

typedef __attribute__((ext_vector_type(4))) float f32x4;
typedef __attribute__((ext_vector_type(2))) int   i32x2;
typedef __attribute__((ext_vector_type(4))) int   i32x4;
typedef __attribute__((ext_vector_type(8))) short short8;

__device__ __forceinline__ unsigned short f2bf(float x) {
  __hip_bfloat16 h = __float2bfloat16(x);
  union { __hip_bfloat16 h1; unsigned short u; } c; c.h1 = h; return c.u;
}
__device__ __forceinline__ unsigned pk2(float a, float b) {
  __hip_bfloat162 h = __float22bfloat162_rn(make_float2(a, b));
  union { __hip_bfloat162 h2; unsigned u; } c; c.h2 = h; return c.u;
}
__device__ __forceinline__ float bf2f(unsigned short u) {
  union { unsigned u32; float f; } c; c.u32 = ((unsigned)u) << 16; return c.f;
}

// ---------------------------------------------------------------------------
// Prep: W1u = edge_w[:256]@G1, W1v = edge_w[256:]@G1 (f32),
// c1 = edge_b@G1 + gb0, W2T/W3T = bf16 transposes of gw1/gw2. grid 513 x 256
// ---------------------------------------------------------------------------
__global__ void k_prep(const float* __restrict__ edge_w, const float* __restrict__ edge_b,
                       const float* __restrict__ gw0, const float* __restrict__ gb0,
                       const float* __restrict__ gw1, const float* __restrict__ gw2,
                       float* __restrict__ W1u, float* __restrict__ W1v,
                       float* __restrict__ c1,
                       unsigned short* __restrict__ W2T, unsigned short* __restrict__ W3T) {
  const int blk = blockIdx.x, t = threadIdx.x;
  __shared__ float eu[256], ev[256];
  if (blk < 256) {
    eu[t] = edge_w[blk * 256 + t];
    ev[t] = edge_w[(256 + blk) * 256 + t];
    __syncthreads();
    float su = 0.f, sv = 0.f;
    for (int o = 0; o < 256; ++o) {
      float gg = gw0[o * 256 + t];
      su += eu[o] * gg; sv += ev[o] * gg;
    }
    W1u[blk * 256 + t] = su;
    W1v[blk * 256 + t] = sv;
  } else if (blk < 512) {
    int m = blk - 256;
    W2T[m * 256 + t] = f2bf(gw1[t * 256 + m]);
    W3T[m * 256 + t] = f2bf(gw2[t * 256 + m]);
  } else {
    float s = gb0[t];
    for (int o = 0; o < 256; ++o) s += edge_b[o] * gw0[o * 256 + t];
    c1[t] = s;
  }
}

// ---------------------------------------------------------------------------
// U1(bf16) = x @ W1u, V1c(f32) = x @ W1v + c1. grid 256 x 1024.
// waves 0-7 -> U, 8-15 -> V; each thread owns 4 rows (ILP-4).
// ---------------------------------------------------------------------------
__global__ void k_uv(const float* __restrict__ x,
                     const float* __restrict__ W1u, const float* __restrict__ W1v,
                     const float* __restrict__ c1,
                     unsigned short* __restrict__ U1, float* __restrict__ V1c) {
  const int blk = blockIdx.x, t = threadIdx.x;
  const int r0 = blk * 8;
  __shared__ float xs[2048];
  if (t < 512) *(f32x4*)(xs + t * 4) = *(const f32x4*)(x + (size_t)r0 * 256 + t * 4);
  __syncthreads();
  const int sel = t >> 9, half = (t >> 8) & 1, col = t & 255;
  const float* W = sel ? W1v : W1u;
  float a[4];
#pragma unroll
  for (int r = 0; r < 4; ++r) a[r] = 0.f;
  const float* xb = xs + (half * 4) * 256;
#pragma unroll 4
  for (int k = 0; k < 256; ++k) {
    float w = W[k * 256 + col];
#pragma unroll
    for (int r = 0; r < 4; ++r) a[r] += xb[r * 256 + k] * w;
  }
  if (sel == 0) {
#pragma unroll
    for (int r = 0; r < 4; ++r) U1[(size_t)(r0 + half * 4 + r) * 256 + col] = f2bf(a[r]);
  } else {
    float c = c1[col];
#pragma unroll
    for (int r = 0; r < 4; ++r) V1c[(size_t)(r0 + half * 4 + r) * 256 + col] = a[r] + c;
  }
}

// ---------------------------------------------------------------------------
// Main fused kernel. Per block (b, itile): 64 pair-rows, 256 features.
// W fragments load global->regs (per-wave-private slices; no LDS staging).
// LDS = h1s[2] (8KB) + h2s (32KB) = 40960B -> 4 blocks/CU.
// GEMM1: 1 barrier/chunk (h1 dbuf). GEMM2: barrier-free.
// ---------------------------------------------------------------------------
__device__ __forceinline__ void write_h1(short8 u, f32x4 v0, f32x4 v1,
                                         unsigned short* dst) {
  float r0 = fmaxf(bf2f((unsigned short)u[0]) + v0.x, 0.f);
  float r1 = fmaxf(bf2f((unsigned short)u[1]) + v0.y, 0.f);
  float r2 = fmaxf(bf2f((unsigned short)u[2]) + v0.z, 0.f);
  float r3 = fmaxf(bf2f((unsigned short)u[3]) + v0.w, 0.f);
  float r4 = fmaxf(bf2f((unsigned short)u[4]) + v1.x, 0.f);
  float r5 = fmaxf(bf2f((unsigned short)u[5]) + v1.y, 0.f);
  float r6 = fmaxf(bf2f((unsigned short)u[6]) + v1.z, 0.f);
  float r7 = fmaxf(bf2f((unsigned short)u[7]) + v1.w, 0.f);
  i32x4 wv = { (int)pk2(r0, r1), (int)pk2(r2, r3), (int)pk2(r4, r5), (int)pk2(r6, r7) };
  *(i32x4*)dst = wv;
}

__launch_bounds__(256, 4)
__global__ void k_main(const unsigned short* __restrict__ U1,
                       const float* __restrict__ V1c,
                       const unsigned short* __restrict__ W2T,
                       const unsigned short* __restrict__ W3T,
                       const float* __restrict__ b2, const float* __restrict__ b3,
                       float* __restrict__ partials) {
  __shared__ unsigned short h1s[2][2048];   // [64 row][32 k], content-swizzled
  __shared__ unsigned short h2s[16384];     // [64 row][256 c2], addr-swizzled

  const int t = threadIdx.x;
  const int bid = blockIdx.x;
  const int wrk = ((bid & 7) << 8) | (bid >> 3);   // XCD swizzle (2048%8==0)
  const int b = wrk >> 6;
  const int wid = t >> 6, lane = t & 63;
  const int q = lane & 15, g = lane >> 4;
  const int mo = wid << 6;

  // h1-staging geometry: thread owns (row, slot), content k-slice ks
  const int row = t >> 2, sl = t & 3;
  const int ks = sl ^ ((row >> 1) & 3);
  const unsigned short* uP = U1 + (size_t)(b * 64 + row) * 256 + ks * 8;
  const float* vP = V1c + (size_t)wrk * 256 + ks * 8;
  unsigned short* const h1w0 = &h1s[0][0] + row * 32 + sl * 8;
  unsigned short* const h1w1 = &h1s[1][0] + row * 32 + sl * 8;

  // A-fragment global bases: feat m = mo+16*mf+q, k = ch*32 + g*8
  const unsigned short* aW2 = W2T + (size_t)(mo + q) * 256 + g * 8;
  const unsigned short* aW3 = W3T + (size_t)(mo + q) * 256 + g * 8;

  // ---- prologue: chunk 0 ----
  short8 a_[4], an_[4];
#pragma unroll
  for (int mf = 0; mf < 4; ++mf) a_[mf] = *(const short8*)(aW2 + mf * 4096);
  {
    short8 u0 = *(const short8*)uP;
    f32x4 v0 = *(const f32x4*)vP;
    f32x4 v1 = *(const f32x4*)(vP + 4);
    write_h1(u0, v0, v1, h1w0);
  }
  __syncthreads();

  f32x4 acc[4][4];
#pragma unroll
  for (int mf = 0; mf < 4; ++mf)
#pragma unroll
    for (int nf = 0; nf < 4; ++nf) acc[mf][nf] = (f32x4){0.f, 0.f, 0.f, 0.f};

  // ---- GEMM1: acc = G2^T * h1^T, K=256 in 8 chunks of 32 ----
  for (int ch = 0; ch < 8; ++ch) {
    const unsigned short* hcur = &h1s[ch & 1][0];
    short8 u_n; f32x4 v0_n, v1_n;
    if (ch < 7) {
#pragma unroll
      for (int mf = 0; mf < 4; ++mf)
        an_[mf] = *(const short8*)(aW2 + mf * 4096 + (ch + 1) * 32);
      u_n  = *(const short8*)(uP + (ch + 1) * 32);
      v0_n = *(const f32x4*)(vP + (ch + 1) * 32);
      v1_n = *(const f32x4*)(vP + (ch + 1) * 32 + 4);
    }
    short8 b_[4];
#pragma unroll
    for (int nf = 0; nf < 4; ++nf) {
      int r = q + 16 * nf;
      b_[nf] = *(const short8*)(hcur + r * 32 + ((g ^ ((r >> 1) & 3)) * 8));
    }
#pragma unroll
    for (int mf = 0; mf < 4; ++mf)
#pragma unroll
      for (int nf = 0; nf < 4; ++nf)
        acc[mf][nf] = __builtin_amdgcn_mfma_f32_16x16x32_bf16(a_[mf], b_[nf], acc[mf][nf], 0, 0, 0);
    if (ch < 7) {
      write_h1(u_n, v0_n, v1_n, ((ch + 1) & 1) ? h1w1 : h1w0);
#pragma unroll
      for (int mf = 0; mf < 4; ++mf) a_[mf] = an_[mf];
      __syncthreads();
    }
  }

  // ---- transition: h2 = relu(acc+b2) -> h2s; prefetch W3 chunk 0 ----
#pragma unroll
  for (int mf = 0; mf < 4; ++mf) a_[mf] = *(const short8*)(aW3 + mf * 4096);
#pragma unroll
  for (int mf = 0; mf < 4; ++mf) {
    int c2b = mo + 16 * mf + 4 * g;
    f32x4 bb = *(const f32x4*)(b2 + c2b);
    int ksw = c2b >> 3, off = c2b & 7;
#pragma unroll
    for (int nf = 0; nf < 4; ++nf) {
      int r = q + 16 * nf;
      f32x4 v = acc[mf][nf];
      float e0 = fmaxf(v.x + bb.x, 0.f), e1 = fmaxf(v.y + bb.y, 0.f);
      float e2 = fmaxf(v.z + bb.z, 0.f), e3 = fmaxf(v.w + bb.w, 0.f);
      i32x2 wv = { (int)pk2(e0, e1), (int)pk2(e2, e3) };
      *(i32x2*)(h2s + r * 256 + ((ksw ^ (r & 7)) * 8) + off) = wv;
    }
  }
  __syncthreads();

  // ---- GEMM2: acc2 = G3^T * h2^T, barrier-free ----
  f32x4 acc2[4][4];
#pragma unroll
  for (int mf = 0; mf < 4; ++mf)
#pragma unroll
    for (int nf = 0; nf < 4; ++nf) acc2[mf][nf] = (f32x4){0.f, 0.f, 0.f, 0.f};

  for (int ch = 0; ch < 8; ++ch) {
    if (ch < 7) {
#pragma unroll
      for (int mf = 0; mf < 4; ++mf)
        an_[mf] = *(const short8*)(aW3 + mf * 4096 + (ch + 1) * 32);
    }
    short8 b_[4];
#pragma unroll
    for (int nf = 0; nf < 4; ++nf) {
      int r = q + 16 * nf;
      int s2 = ch * 4 + g;
      b_[nf] = *(const short8*)(h2s + r * 256 + ((s2 ^ (r & 7)) * 8));
    }
#pragma unroll
    for (int mf = 0; mf < 4; ++mf)
#pragma unroll
      for (int nf = 0; nf < 4; ++nf)
        acc2[mf][nf] = __builtin_amdgcn_mfma_f32_16x16x32_bf16(a_[mf], b_[nf], acc2[mf][nf], 0, 0, 0);
    if (ch < 7) {
#pragma unroll
      for (int mf = 0; mf < 4; ++mf) a_[mf] = an_[mf];
    }
  }

  // ---- h3 = relu(acc2 + b3); row-sum (in-frag + q-butterfly); store ----
#pragma unroll
  for (int mf = 0; mf < 4; ++mf) {
    int n3b = mo + 16 * mf + 4 * g;
    f32x4 bb = *(const f32x4*)(b3 + n3b);
    f32x4 sum = (f32x4){0.f, 0.f, 0.f, 0.f};
#pragma unroll
    for (int nf = 0; nf < 4; ++nf) {
      f32x4 v = acc2[mf][nf];
      sum.x += fmaxf(v.x + bb.x, 0.f);
      sum.y += fmaxf(v.y + bb.y, 0.f);
      sum.z += fmaxf(v.z + bb.z, 0.f);
      sum.w += fmaxf(v.w + bb.w, 0.f);
    }
#pragma unroll
    for (int msk = 1; msk < 16; msk <<= 1) {
      sum.x += __shfl_xor(sum.x, msk);
      sum.y += __shfl_xor(sum.y, msk);
      sum.z += __shfl_xor(sum.z, msk);
      sum.w += __shfl_xor(sum.w, msk);
    }
    if (q == 0) *(f32x4*)(partials + (size_t)wrk * 256 + n3b) = sum;
  }
}

// ---------------------------------------------------------------------------
// Reduce partials per batch + f-MLP (f32), ILP-4. grid 32 x 256.
// ---------------------------------------------------------------------------
__global__ void k_fmlp(const float* __restrict__ partials,
                       const float* __restrict__ f1w, const float* __restrict__ f1b,
                       const float* __restrict__ f2w, const float* __restrict__ f2b,
                       const float* __restrict__ f3w, const float* __restrict__ f3b,
                       float* __restrict__ out) {
  const int b = blockIdx.x, t = threadIdx.x;
  __shared__ float xg[256], x1[256], x2[256];
  {
    const float* p = partials + (size_t)(b * 64) * 256 + t;
    float s0 = 0.f, s1 = 0.f, s2 = 0.f, s3 = 0.f;
#pragma unroll 4
    for (int k = 0; k < 16; ++k) {
      s0 += p[(k)      * 256];
      s1 += p[(k + 16) * 256];
      s2 += p[(k + 32) * 256];
      s3 += p[(k + 48) * 256];
    }
    xg[t] = (s0 + s1) + (s2 + s3);
  }
  __syncthreads();
  {
    float a0 = 0.f, a1 = 0.f, a2 = 0.f, a3 = 0.f;
#pragma unroll 4
    for (int k = 0; k < 64; ++k) {
      a0 += xg[k]       * f1w[(k)       * 256 + t];
      a1 += xg[k + 64]  * f1w[(k + 64)  * 256 + t];
      a2 += xg[k + 128] * f1w[(k + 128) * 256 + t];
      a3 += xg[k + 192] * f1w[(k + 192) * 256 + t];
    }
    x1[t] = fmaxf((a0 + a1) + (a2 + a3) + f1b[t], 0.f);
  }
  __syncthreads();
  {
    float a0 = 0.f, a1 = 0.f, a2 = 0.f, a3 = 0.f;
#pragma unroll 4
    for (int k = 0; k < 64; ++k) {
      a0 += x1[k]       * f2w[(k)       * 256 + t];
      a1 += x1[k + 64]  * f2w[(k + 64)  * 256 + t];
      a2 += x1[k + 128] * f2w[(k + 128) * 256 + t];
      a3 += x1[k + 192] * f2w[(k + 192) * 256 + t];
    }
    x2[t] = fmaxf((a0 + a1) + (a2 + a3) + f2b[t], 0.f);
  }
  __syncthreads();
  if (t < 128) {
    float a0 = 0.f, a1 = 0.f, a2 = 0.f, a3 = 0.f;
#pragma unroll 4
    for (int k = 0; k < 64; ++k) {
      a0 += x2[k]       * f3w[(k)       * 128 + t];
      a1 += x2[k + 64]  * f3w[(k + 64)  * 128 + t];
      a2 += x2[k + 128] * f3w[(k + 128) * 128 + t];
      a3 += x2[k + 192] * f3w[(k + 192) * 128 + t];
    }
    out[b * 128 + t] = (a0 + a1) + (a2 + a3) + f3b[t];
  }
}

__global__ void k_zero(float* __restrict__ out, int n) {
  int i = blockIdx.x * 256 + threadIdx.x;
  if (i < n) out[i] = 0.f;
}

// ---------------------------------------------------------------------------
extern "C" void kernel_launch(void* const* d_in, const int* in_sizes, int n_in,
                              void* d_out, int out_size, void* d_ws, size_t ws_size,
                              hipStream_t stream) {
  const float* x      = (const float*)d_in[0];
  const float* edge_w = (const float*)d_in[1];
  const float* edge_b = (const float*)d_in[2];
  const float *gw0, *gw1, *gw2, *gb0, *gb1, *gb2;
  const float *f1w, *f1b, *f2w, *f2b, *f3w, *f3b;

  if (n_in >= 15 && in_sizes[3] == 65536 && in_sizes[4] == 65536 && in_sizes[5] == 65536) {
    gw0 = (const float*)d_in[3]; gw1 = (const float*)d_in[4]; gw2 = (const float*)d_in[5];
    gb0 = (const float*)d_in[6]; gb1 = (const float*)d_in[7]; gb2 = (const float*)d_in[8];
    f1w = (const float*)d_in[9];  f1b = (const float*)d_in[10];
    f2w = (const float*)d_in[11]; f2b = (const float*)d_in[12];
    f3w = (const float*)d_in[13]; f3b = (const float*)d_in[14];
  } else if (n_in >= 15 && in_sizes[3] == 65536 && in_sizes[4] == 256) {
    gw0 = (const float*)d_in[3]; gb0 = (const float*)d_in[4];
    gw1 = (const float*)d_in[5]; gb1 = (const float*)d_in[6];
    gw2 = (const float*)d_in[7]; gb2 = (const float*)d_in[8];
    f1w = (const float*)d_in[9];  f1b = (const float*)d_in[10];
    f2w = (const float*)d_in[11]; f2b = (const float*)d_in[12];
    f3w = (const float*)d_in[13]; f3b = (const float*)d_in[14];
  } else {
    const float* gws = (const float*)d_in[3];
    const float* gbs = (const float*)d_in[4];
    gw0 = gws;          gw1 = gws + 65536;  gw2 = gws + 131072;
    gb0 = gbs;          gb1 = gbs + 256;    gb2 = gbs + 512;
    f1w = (const float*)d_in[5];  f1b = (const float*)d_in[6];
    f2w = (const float*)d_in[7];  f2b = (const float*)d_in[8];
    f3w = (const float*)d_in[9];  f3b = (const float*)d_in[10];
  }

  char* ws = (char*)d_ws;
  float*          W1u      = (float*)(ws);                    // 256KB
  float*          W1v      = (float*)(ws + 262144);           // 256KB
  float*          c1       = (float*)(ws + 524288);           // 1KB
  unsigned short* W2T      = (unsigned short*)(ws + 525312);  // 128KB
  unsigned short* W3T      = (unsigned short*)(ws + 656384);  // 128KB
  unsigned short* U1       = (unsigned short*)(ws + 787456);  // 1MB   (bf16)
  float*          V1c      = (float*)(ws + 1836032);          // 2MB
  float*          partials = (float*)(ws + 3933184);          // 2MB
  const size_t need = 6030336;
  (void)out_size; (void)n_in;

  if (ws_size < need) {
    k_zero<<<dim3((out_size + 255) / 256), dim3(256), 0, stream>>>((float*)d_out, out_size);
    return;
  }

  k_prep<<<dim3(513), dim3(256), 0, stream>>>(edge_w, edge_b, gw0, gb0, gw1, gw2,
                                              W1u, W1v, c1, W2T, W3T);
  k_uv<<<dim3(256), dim3(1024), 0, stream>>>(x, W1u, W1v, c1, U1, V1c);
  k_main<<<dim3(2048), dim3(256), 0, stream>>>(U1, V1c, W2T, W3T, gb1, gb2, partials);
  k_fmlp<<<dim3(32), dim3(256), 0, stream>>>(partials, f1w, f1b, f2w, f2b, f3w, f3b,
                                             (float*)d_out);
}

// Round 5
// 86.449 us; speedup vs baseline: 1.6088x; 1.6088x over previous
//
#include <hip/hip_runtime.h>
#include <hip/hip_bf16.h>

typedef __attribute__((ext_vector_type(4))) float f32x4;
typedef __attribute__((ext_vector_type(2))) int   i32x2;
typedef __attribute__((ext_vector_type(4))) int   i32x4;
typedef __attribute__((ext_vector_type(8))) short short8;

__device__ __forceinline__ unsigned short f2bf(float x) {
  __hip_bfloat16 h = __float2bfloat16(x);
  union { __hip_bfloat16 h1; unsigned short u; } c; c.h1 = h; return c.u;
}
__device__ __forceinline__ unsigned pk2(float a, float b) {
  __hip_bfloat162 h = __float22bfloat162_rn(make_float2(a, b));
  union { __hip_bfloat162 h2; unsigned u; } c; c.h2 = h; return c.u;
}
__device__ __forceinline__ float bf2f(unsigned short u) {
  union { unsigned u32; float f; } c; c.u32 = ((unsigned)u) << 16; return c.f;
}

// ---------------------------------------------------------------------------
// Prep. grid 321 x 256:
//   blk<256   : W1u = edge_w[:256]@G1, W1v = edge_w[256:]@G1 (f32)
//   blk==256  : c1 = edge_b@G1 + gb0
//   blk 257.. : W2R/W3R = gw1/gw2 in MFMA-fragment-scheduled bf16 layout:
//               W2R[((w*8+ch)*4+mf)*512 + (g*16+q)*8 + e] = gw1[ch*32+g*8+e][w*64+mf*16+q]
//               so each (wave,chunk,mf) A-fragment is a contiguous 1KB burst.
// ---------------------------------------------------------------------------
__global__ void k_prep(const float* __restrict__ edge_w, const float* __restrict__ edge_b,
                       const float* __restrict__ gw0, const float* __restrict__ gb0,
                       const float* __restrict__ gw1, const float* __restrict__ gw2,
                       float* __restrict__ W1u, float* __restrict__ W1v,
                       float* __restrict__ c1,
                       unsigned short* __restrict__ W2R, unsigned short* __restrict__ W3R) {
  const int blk = blockIdx.x, t = threadIdx.x;
  __shared__ float eu[256], ev[256];
  if (blk < 256) {
    eu[t] = edge_w[blk * 256 + t];
    ev[t] = edge_w[(256 + blk) * 256 + t];
    __syncthreads();
    float su = 0.f, sv = 0.f;
    for (int o = 0; o < 256; ++o) {
      float gg = gw0[o * 256 + t];
      su += eu[o] * gg; sv += ev[o] * gg;
    }
    W1u[blk * 256 + t] = su;
    W1v[blk * 256 + t] = sv;
  } else if (blk == 256) {
    float s = gb0[t];
    for (int o = 0; o < 256; ++o) s += edge_b[o] * gw0[o * 256 + t];
    c1[t] = s;
  } else {
    int p = blk - 257;                       // 0..63: [0,32)->W2R, [32,64)->W3R
    const float* src = (p < 32) ? gw1 : gw2;
    unsigned short* dst = (p < 32) ? W2R : W3R;
    p &= 31;
    int w = p >> 3, ch = p & 7;
    int mf = t >> 6, lane = t & 63, q = lane & 15, g = lane >> 4;
    int base = ((w * 8 + ch) * 4 + mf) * 512 + lane * 8;
    int m = w * 64 + mf * 16 + q;
#pragma unroll
    for (int e = 0; e < 8; ++e) {
      int k = ch * 32 + g * 8 + e;
      dst[base + e] = f2bf(src[k * 256 + m]);
    }
  }
}

// ---------------------------------------------------------------------------
// U1(bf16) = x @ W1u, V1c(f32) = x @ W1v + c1. grid 256 x 1024.
// ---------------------------------------------------------------------------
__global__ void k_uv(const float* __restrict__ x,
                     const float* __restrict__ W1u, const float* __restrict__ W1v,
                     const float* __restrict__ c1,
                     unsigned short* __restrict__ U1, float* __restrict__ V1c) {
  const int blk = blockIdx.x, t = threadIdx.x;
  const int r0 = blk * 8;
  __shared__ float xs[2048];
  if (t < 512) *(f32x4*)(xs + t * 4) = *(const f32x4*)(x + (size_t)r0 * 256 + t * 4);
  __syncthreads();
  const int sel = t >> 9, half = (t >> 8) & 1, col = t & 255;
  const float* W = sel ? W1v : W1u;
  float a[4];
#pragma unroll
  for (int r = 0; r < 4; ++r) a[r] = 0.f;
  const float* xb = xs + (half * 4) * 256;
#pragma unroll 4
  for (int k = 0; k < 256; ++k) {
    float w = W[k * 256 + col];
#pragma unroll
    for (int r = 0; r < 4; ++r) a[r] += xb[r * 256 + k] * w;
  }
  if (sel == 0) {
#pragma unroll
    for (int r = 0; r < 4; ++r) U1[(size_t)(r0 + half * 4 + r) * 256 + col] = f2bf(a[r]);
  } else {
    float c = c1[col];
#pragma unroll
    for (int r = 0; r < 4; ++r) V1c[(size_t)(r0 + half * 4 + r) * 256 + col] = a[r] + c;
  }
}

// ---------------------------------------------------------------------------
// Main fused kernel. Per block (b, itile): 64 pair-rows, 256 features.
// W fragments: coalesced 1KB wave-bursts from W2R/W3R, global->reg, 1-chunk prefetch.
// LDS = h1s[2] (8KB) + h2s (32KB) = 40960B; VGPR cap via (256,3) -> 3 blocks/CU.
// GEMM1: 1 barrier/chunk (h1 dbuf). GEMM2: barrier-free. Epilogue: LDS reduce.
// ---------------------------------------------------------------------------
__device__ __forceinline__ void write_h1(short8 u, f32x4 v0, f32x4 v1,
                                         unsigned short* dst) {
  float r0 = fmaxf(bf2f((unsigned short)u[0]) + v0.x, 0.f);
  float r1 = fmaxf(bf2f((unsigned short)u[1]) + v0.y, 0.f);
  float r2 = fmaxf(bf2f((unsigned short)u[2]) + v0.z, 0.f);
  float r3 = fmaxf(bf2f((unsigned short)u[3]) + v0.w, 0.f);
  float r4 = fmaxf(bf2f((unsigned short)u[4]) + v1.x, 0.f);
  float r5 = fmaxf(bf2f((unsigned short)u[5]) + v1.y, 0.f);
  float r6 = fmaxf(bf2f((unsigned short)u[6]) + v1.z, 0.f);
  float r7 = fmaxf(bf2f((unsigned short)u[7]) + v1.w, 0.f);
  i32x4 wv = { (int)pk2(r0, r1), (int)pk2(r2, r3), (int)pk2(r4, r5), (int)pk2(r6, r7) };
  *(i32x4*)dst = wv;
}

__launch_bounds__(256, 3)
__global__ void k_main(const unsigned short* __restrict__ U1,
                       const float* __restrict__ V1c,
                       const unsigned short* __restrict__ W2R,
                       const unsigned short* __restrict__ W3R,
                       const float* __restrict__ b2, const float* __restrict__ b3,
                       float* __restrict__ partials) {
  __shared__ unsigned short h1s[2][2048];   // [64 row][32 k], content-swizzled
  __shared__ unsigned short h2s[16384];     // [64 row][256 c2], addr-swizzled; reused as f32 scratch

  const int t = threadIdx.x;
  const int bid = blockIdx.x;
  const int wrk = ((bid & 7) << 8) | (bid >> 3);   // XCD swizzle (2048%8==0)
  const int b = wrk >> 6;
  const int wid = t >> 6, lane = t & 63;
  const int q = lane & 15, g = lane >> 4;
  const int mo = wid << 6;

  // h1-staging geometry: thread owns (row, slot), content k-slice ks
  const int row = t >> 2, sl = t & 3;
  const int ks = sl ^ ((row >> 1) & 3);
  const unsigned short* uP = U1 + (size_t)(b * 64 + row) * 256 + ks * 8;
  const float* vP = V1c + (size_t)wrk * 256 + ks * 8;
  unsigned short* const h1w0 = &h1s[0][0] + row * 32 + sl * 8;
  unsigned short* const h1w1 = &h1s[1][0] + row * 32 + sl * 8;

  // A-fragment bases: fragment (wid,ch,mf) at W2R[((wid*8+ch)*4+mf)*512 + lane*8]
  const unsigned short* aW2 = W2R + (size_t)wid * 16384 + lane * 8;
  const unsigned short* aW3 = W3R + (size_t)wid * 16384 + lane * 8;

  // ---- prologue: chunk 0 ----
  short8 a_[4], an_[4];
#pragma unroll
  for (int mf = 0; mf < 4; ++mf) a_[mf] = *(const short8*)(aW2 + mf * 512);
  {
    short8 u0 = *(const short8*)uP;
    f32x4 v0 = *(const f32x4*)vP;
    f32x4 v1 = *(const f32x4*)(vP + 4);
    write_h1(u0, v0, v1, h1w0);
  }
  __syncthreads();

  f32x4 acc[4][4];
#pragma unroll
  for (int mf = 0; mf < 4; ++mf)
#pragma unroll
    for (int nf = 0; nf < 4; ++nf) acc[mf][nf] = (f32x4){0.f, 0.f, 0.f, 0.f};

  // ---- GEMM1: acc = G2^T * h1^T, K=256 in 8 chunks of 32 ----
  for (int ch = 0; ch < 8; ++ch) {
    const unsigned short* hcur = &h1s[ch & 1][0];
    short8 u_n; f32x4 v0_n, v1_n;
    if (ch < 7) {
#pragma unroll
      for (int mf = 0; mf < 4; ++mf)
        an_[mf] = *(const short8*)(aW2 + (ch + 1) * 2048 + mf * 512);
      u_n  = *(const short8*)(uP + (ch + 1) * 32);
      v0_n = *(const f32x4*)(vP + (ch + 1) * 32);
      v1_n = *(const f32x4*)(vP + (ch + 1) * 32 + 4);
    }
    short8 b_[4];
#pragma unroll
    for (int nf = 0; nf < 4; ++nf) {
      int r = q + 16 * nf;
      b_[nf] = *(const short8*)(hcur + r * 32 + ((g ^ ((r >> 1) & 3)) * 8));
    }
#pragma unroll
    for (int mf = 0; mf < 4; ++mf)
#pragma unroll
      for (int nf = 0; nf < 4; ++nf)
        acc[mf][nf] = __builtin_amdgcn_mfma_f32_16x16x32_bf16(a_[mf], b_[nf], acc[mf][nf], 0, 0, 0);
    if (ch < 7) {
      write_h1(u_n, v0_n, v1_n, ((ch + 1) & 1) ? h1w1 : h1w0);
#pragma unroll
      for (int mf = 0; mf < 4; ++mf) a_[mf] = an_[mf];
      __syncthreads();
    }
  }

  // ---- transition: h2 = relu(acc+b2) -> h2s; prefetch W3 chunk 0 ----
#pragma unroll
  for (int mf = 0; mf < 4; ++mf) a_[mf] = *(const short8*)(aW3 + mf * 512);
#pragma unroll
  for (int mf = 0; mf < 4; ++mf) {
    int c2b = mo + 16 * mf + 4 * g;
    f32x4 bb = *(const f32x4*)(b2 + c2b);
    int ksw = c2b >> 3, off = c2b & 7;
#pragma unroll
    for (int nf = 0; nf < 4; ++nf) {
      int r = q + 16 * nf;
      f32x4 v = acc[mf][nf];
      float e0 = fmaxf(v.x + bb.x, 0.f), e1 = fmaxf(v.y + bb.y, 0.f);
      float e2 = fmaxf(v.z + bb.z, 0.f), e3 = fmaxf(v.w + bb.w, 0.f);
      i32x2 wv = { (int)pk2(e0, e1), (int)pk2(e2, e3) };
      *(i32x2*)(h2s + r * 256 + ((ksw ^ (r & 7)) * 8) + off) = wv;
    }
  }
  __syncthreads();

  // ---- GEMM2: acc2 = G3^T * h2^T, barrier-free ----
  f32x4 acc2[4][4];
#pragma unroll
  for (int mf = 0; mf < 4; ++mf)
#pragma unroll
    for (int nf = 0; nf < 4; ++nf) acc2[mf][nf] = (f32x4){0.f, 0.f, 0.f, 0.f};

  for (int ch = 0; ch < 8; ++ch) {
    if (ch < 7) {
#pragma unroll
      for (int mf = 0; mf < 4; ++mf)
        an_[mf] = *(const short8*)(aW3 + (ch + 1) * 2048 + mf * 512);
    }
    short8 b_[4];
#pragma unroll
    for (int nf = 0; nf < 4; ++nf) {
      int r = q + 16 * nf;
      int s2 = ch * 4 + g;
      b_[nf] = *(const short8*)(h2s + r * 256 + ((s2 ^ (r & 7)) * 8));
    }
#pragma unroll
    for (int mf = 0; mf < 4; ++mf)
#pragma unroll
      for (int nf = 0; nf < 4; ++nf)
        acc2[mf][nf] = __builtin_amdgcn_mfma_f32_16x16x32_bf16(a_[mf], b_[nf], acc2[mf][nf], 0, 0, 0);
    if (ch < 7) {
#pragma unroll
      for (int mf = 0; mf < 4; ++mf) a_[mf] = an_[mf];
    }
  }
  __syncthreads();   // all h2s reads done before scratch reuse

  // ---- h3 = relu(acc2 + b3); row-sum: in-frag + padded-LDS transpose reduce ----
  float* scr = (float*)&h2s[0];            // [16 q][264 pad] f32 = 16.5KB
#pragma unroll
  for (int mf = 0; mf < 4; ++mf) {
    int n3b = mo + 16 * mf + 4 * g;
    f32x4 bb = *(const f32x4*)(b3 + n3b);
    f32x4 sum = (f32x4){0.f, 0.f, 0.f, 0.f};
#pragma unroll
    for (int nf = 0; nf < 4; ++nf) {
      f32x4 v = acc2[mf][nf];
      sum.x += fmaxf(v.x + bb.x, 0.f);
      sum.y += fmaxf(v.y + bb.y, 0.f);
      sum.z += fmaxf(v.z + bb.z, 0.f);
      sum.w += fmaxf(v.w + bb.w, 0.f);
    }
    *(f32x4*)(scr + q * 264 + n3b) = sum;
  }
  __syncthreads();
  float s = 0.f;
#pragma unroll
  for (int q2 = 0; q2 < 16; ++q2) s += scr[q2 * 264 + t];
  partials[(size_t)wrk * 256 + t] = s;
}

// ---------------------------------------------------------------------------
// Reduce partials per batch + f-MLP (f32). grid 32 x 256.
// ---------------------------------------------------------------------------
__global__ void k_fmlp(const float* __restrict__ partials,
                       const float* __restrict__ f1w, const float* __restrict__ f1b,
                       const float* __restrict__ f2w, const float* __restrict__ f2b,
                       const float* __restrict__ f3w, const float* __restrict__ f3b,
                       float* __restrict__ out) {
  const int b = blockIdx.x, t = threadIdx.x;
  __shared__ float xg[256], x1[256], x2[256];
  {
    const float* p = partials + (size_t)(b * 64) * 256 + t;
    float s[8];
#pragma unroll
    for (int i = 0; i < 8; ++i) s[i] = 0.f;
#pragma unroll
    for (int k = 0; k < 8; ++k)
#pragma unroll
      for (int i = 0; i < 8; ++i) s[i] += p[(k * 8 + i) * 256];
    float tot = 0.f;
#pragma unroll
    for (int i = 0; i < 8; ++i) tot += s[i];
    xg[t] = tot;
  }
  __syncthreads();
  {
    float a0 = 0.f, a1 = 0.f, a2 = 0.f, a3 = 0.f;
#pragma unroll 4
    for (int k = 0; k < 64; ++k) {
      a0 += xg[k]       * f1w[(k)       * 256 + t];
      a1 += xg[k + 64]  * f1w[(k + 64)  * 256 + t];
      a2 += xg[k + 128] * f1w[(k + 128) * 256 + t];
      a3 += xg[k + 192] * f1w[(k + 192) * 256 + t];
    }
    x1[t] = fmaxf((a0 + a1) + (a2 + a3) + f1b[t], 0.f);
  }
  __syncthreads();
  {
    float a0 = 0.f, a1 = 0.f, a2 = 0.f, a3 = 0.f;
#pragma unroll 4
    for (int k = 0; k < 64; ++k) {
      a0 += x1[k]       * f2w[(k)       * 256 + t];
      a1 += x1[k + 64]  * f2w[(k + 64)  * 256 + t];
      a2 += x1[k + 128] * f2w[(k + 128) * 256 + t];
      a3 += x1[k + 192] * f2w[(k + 192) * 256 + t];
    }
    x2[t] = fmaxf((a0 + a1) + (a2 + a3) + f2b[t], 0.f);
  }
  __syncthreads();
  if (t < 128) {
    float a0 = 0.f, a1 = 0.f, a2 = 0.f, a3 = 0.f;
#pragma unroll 4
    for (int k = 0; k < 64; ++k) {
      a0 += x2[k]       * f3w[(k)       * 128 + t];
      a1 += x2[k + 64]  * f3w[(k + 64)  * 128 + t];
      a2 += x2[k + 128] * f3w[(k + 128) * 128 + t];
      a3 += x2[k + 192] * f3w[(k + 192) * 128 + t];
    }
    out[b * 128 + t] = (a0 + a1) + (a2 + a3) + f3b[t];
  }
}

__global__ void k_zero(float* __restrict__ out, int n) {
  int i = blockIdx.x * 256 + threadIdx.x;
  if (i < n) out[i] = 0.f;
}

// ---------------------------------------------------------------------------
extern "C" void kernel_launch(void* const* d_in, const int* in_sizes, int n_in,
                              void* d_out, int out_size, void* d_ws, size_t ws_size,
                              hipStream_t stream) {
  const float* x      = (const float*)d_in[0];
  const float* edge_w = (const float*)d_in[1];
  const float* edge_b = (const float*)d_in[2];
  const float *gw0, *gw1, *gw2, *gb0, *gb1, *gb2;
  const float *f1w, *f1b, *f2w, *f2b, *f3w, *f3b;

  if (n_in >= 15 && in_sizes[3] == 65536 && in_sizes[4] == 65536 && in_sizes[5] == 65536) {
    gw0 = (const float*)d_in[3]; gw1 = (const float*)d_in[4]; gw2 = (const float*)d_in[5];
    gb0 = (const float*)d_in[6]; gb1 = (const float*)d_in[7]; gb2 = (const float*)d_in[8];
    f1w = (const float*)d_in[9];  f1b = (const float*)d_in[10];
    f2w = (const float*)d_in[11]; f2b = (const float*)d_in[12];
    f3w = (const float*)d_in[13]; f3b = (const float*)d_in[14];
  } else if (n_in >= 15 && in_sizes[3] == 65536 && in_sizes[4] == 256) {
    gw0 = (const float*)d_in[3]; gb0 = (const float*)d_in[4];
    gw1 = (const float*)d_in[5]; gb1 = (const float*)d_in[6];
    gw2 = (const float*)d_in[7]; gb2 = (const float*)d_in[8];
    f1w = (const float*)d_in[9];  f1b = (const float*)d_in[10];
    f2w = (const float*)d_in[11]; f2b = (const float*)d_in[12];
    f3w = (const float*)d_in[13]; f3b = (const float*)d_in[14];
  } else {
    const float* gws = (const float*)d_in[3];
    const float* gbs = (const float*)d_in[4];
    gw0 = gws;          gw1 = gws + 65536;  gw2 = gws + 131072;
    gb0 = gbs;          gb1 = gbs + 256;    gb2 = gbs + 512;
    f1w = (const float*)d_in[5];  f1b = (const float*)d_in[6];
    f2w = (const float*)d_in[7];  f2b = (const float*)d_in[8];
    f3w = (const float*)d_in[9];  f3b = (const float*)d_in[10];
  }

  char* ws = (char*)d_ws;
  float*          W1u      = (float*)(ws);                    // 256KB
  float*          W1v      = (float*)(ws + 262144);           // 256KB
  float*          c1       = (float*)(ws + 524288);           // 1KB
  unsigned short* W2R      = (unsigned short*)(ws + 525312);  // 128KB
  unsigned short* W3R      = (unsigned short*)(ws + 656384);  // 128KB
  unsigned short* U1       = (unsigned short*)(ws + 787456);  // 1MB   (bf16)
  float*          V1c      = (float*)(ws + 1836032);          // 2MB
  float*          partials = (float*)(ws + 3933184);          // 2MB
  const size_t need = 6030336;
  (void)out_size; (void)n_in;

  if (ws_size < need) {
    k_zero<<<dim3((out_size + 255) / 256), dim3(256), 0, stream>>>((float*)d_out, out_size);
    return;
  }

  k_prep<<<dim3(321), dim3(256), 0, stream>>>(edge_w, edge_b, gw0, gb0, gw1, gw2,
                                              W1u, W1v, c1, W2R, W3R);
  k_uv<<<dim3(256), dim3(1024), 0, stream>>>(x, W1u, W1v, c1, U1, V1c);
  k_main<<<dim3(2048), dim3(256), 0, stream>>>(U1, V1c, W2R, W3R, gb1, gb2, partials);
  k_fmlp<<<dim3(32), dim3(256), 0, stream>>>(partials, f1w, f1b, f2w, f2b, f3w, f3b,
                                             (float*)d_out);
}

// Round 6
// 79.277 us; speedup vs baseline: 1.7543x; 1.0905x over previous
//
#include <hip/hip_runtime.h>
#include <hip/hip_bf16.h>

typedef __attribute__((ext_vector_type(4))) float f32x4;
typedef __attribute__((ext_vector_type(2))) int   i32x2;
typedef __attribute__((ext_vector_type(4))) int   i32x4;
typedef __attribute__((ext_vector_type(8))) short short8;

__device__ __forceinline__ unsigned short f2bf(float x) {
  __hip_bfloat16 h = __float2bfloat16(x);
  union { __hip_bfloat16 h1; unsigned short u; } c; c.h1 = h; return c.u;
}
__device__ __forceinline__ unsigned pk2(float a, float b) {
  __hip_bfloat162 h = __float22bfloat162_rn(make_float2(a, b));
  union { __hip_bfloat162 h2; unsigned u; } c; c.h2 = h; return c.u;
}
__device__ __forceinline__ float bf2f(unsigned short u) {
  union { unsigned u32; float f; } c; c.u32 = ((unsigned)u) << 16; return c.f;
}

// ---------------------------------------------------------------------------
// Prep. grid 321 x 256:
//   blk<256   : W1u = edge_w[:256]@G1, W1v = edge_w[256:]@G1 (f32)
//   blk==256  : c1 = edge_b@G1 + gb0
//   blk 257.. : W2R/W3R = gw1/gw2 in MFMA-fragment-scheduled bf16 layout:
//               fragment (wave w, chunk ch, mf) is a contiguous 1KB burst.
// ---------------------------------------------------------------------------
__global__ void k_prep(const float* __restrict__ edge_w, const float* __restrict__ edge_b,
                       const float* __restrict__ gw0, const float* __restrict__ gb0,
                       const float* __restrict__ gw1, const float* __restrict__ gw2,
                       float* __restrict__ W1u, float* __restrict__ W1v,
                       float* __restrict__ c1,
                       unsigned short* __restrict__ W2R, unsigned short* __restrict__ W3R) {
  const int blk = blockIdx.x, t = threadIdx.x;
  __shared__ float eu[256], ev[256];
  if (blk < 256) {
    eu[t] = edge_w[blk * 256 + t];
    ev[t] = edge_w[(256 + blk) * 256 + t];
    __syncthreads();
    float su = 0.f, sv = 0.f;
    for (int o = 0; o < 256; ++o) {
      float gg = gw0[o * 256 + t];
      su += eu[o] * gg; sv += ev[o] * gg;
    }
    W1u[blk * 256 + t] = su;
    W1v[blk * 256 + t] = sv;
  } else if (blk == 256) {
    float s = gb0[t];
    for (int o = 0; o < 256; ++o) s += edge_b[o] * gw0[o * 256 + t];
    c1[t] = s;
  } else {
    int p = blk - 257;                       // 0..63: [0,32)->W2R, [32,64)->W3R
    const float* src = (p < 32) ? gw1 : gw2;
    unsigned short* dst = (p < 32) ? W2R : W3R;
    p &= 31;
    int w = p >> 3, ch = p & 7;
    int mf = t >> 6, lane = t & 63, q = lane & 15, g = lane >> 4;
    int base = ((w * 8 + ch) * 4 + mf) * 512 + lane * 8;
    int m = w * 64 + mf * 16 + q;
#pragma unroll
    for (int e = 0; e < 8; ++e) {
      int k = ch * 32 + g * 8 + e;
      dst[base + e] = f2bf(src[k * 256 + m]);
    }
  }
}

// ---------------------------------------------------------------------------
// U1(bf16) = x @ W1u, V1c(f32) = x @ W1v + c1.  grid 256 x 1024, split-K:
// thread = (sel: U/V, kh: k-half, col); every W element read exactly once.
// ---------------------------------------------------------------------------
__global__ void k_uv(const float* __restrict__ x,
                     const float* __restrict__ W1u, const float* __restrict__ W1v,
                     const float* __restrict__ c1,
                     unsigned short* __restrict__ U1, float* __restrict__ V1c) {
  const int blk = blockIdx.x, t = threadIdx.x;
  const int r0 = blk * 8;
  __shared__ float xs[2048];
  __shared__ float pl[8 * 512];            // [r][sel*256+col] partials from kh=1
  if (t < 512) *(f32x4*)(xs + t * 4) = *(const f32x4*)(x + (size_t)r0 * 256 + t * 4);
  __syncthreads();
  const int sel = t >> 9, kh = (t >> 8) & 1, col = t & 255;
  const float* W = (sel ? W1v : W1u) + (size_t)kh * 128 * 256;
  const float* xb = xs + kh * 128;
  float a[8];
#pragma unroll
  for (int r = 0; r < 8; ++r) a[r] = 0.f;
#pragma unroll 4
  for (int k = 0; k < 128; ++k) {
    float w = W[k * 256 + col];
#pragma unroll
    for (int r = 0; r < 8; ++r) a[r] += xb[r * 256 + k] * w;
  }
  if (kh == 1) {
#pragma unroll
    for (int r = 0; r < 8; ++r) pl[r * 512 + sel * 256 + col] = a[r];
  }
  __syncthreads();
  if (kh == 0) {
#pragma unroll
    for (int r = 0; r < 8; ++r) a[r] += pl[r * 512 + sel * 256 + col];
    if (sel == 0) {
#pragma unroll
      for (int r = 0; r < 8; ++r) U1[(size_t)(r0 + r) * 256 + col] = f2bf(a[r]);
    } else {
      float c = c1[col];
#pragma unroll
      for (int r = 0; r < 8; ++r) V1c[(size_t)(r0 + r) * 256 + col] = a[r] + c;
    }
  }
}

// ---------------------------------------------------------------------------
// Main fused kernel, 3-phase / 5-barrier. Per block (b, itile): 64 rows.
// One 32KB LDS buffer reused: h1 (GEMM1 input) -> h2 (GEMM2 input) -> f32 scratch.
// Element (r,k) at hbuf[r*256 + ((k>>3) ^ (r&7))*8 + (k&7)] (conflict-free).
// W fragments: contiguous 1KB wave-bursts from W2R/W3R (global->reg, prefetch 1).
// ---------------------------------------------------------------------------
__device__ __forceinline__ void write_h1(short8 u, f32x4 v0, f32x4 v1,
                                         unsigned short* dst) {
  float r0 = fmaxf(bf2f((unsigned short)u[0]) + v0.x, 0.f);
  float r1 = fmaxf(bf2f((unsigned short)u[1]) + v0.y, 0.f);
  float r2 = fmaxf(bf2f((unsigned short)u[2]) + v0.z, 0.f);
  float r3 = fmaxf(bf2f((unsigned short)u[3]) + v0.w, 0.f);
  float r4 = fmaxf(bf2f((unsigned short)u[4]) + v1.x, 0.f);
  float r5 = fmaxf(bf2f((unsigned short)u[5]) + v1.y, 0.f);
  float r6 = fmaxf(bf2f((unsigned short)u[6]) + v1.z, 0.f);
  float r7 = fmaxf(bf2f((unsigned short)u[7]) + v1.w, 0.f);
  i32x4 wv = { (int)pk2(r0, r1), (int)pk2(r2, r3), (int)pk2(r4, r5), (int)pk2(r6, r7) };
  *(i32x4*)dst = wv;
}

__launch_bounds__(256, 3)
__global__ void k_main(const unsigned short* __restrict__ U1,
                       const float* __restrict__ V1c,
                       const unsigned short* __restrict__ W2R,
                       const unsigned short* __restrict__ W3R,
                       const float* __restrict__ b2, const float* __restrict__ b3,
                       float* __restrict__ partials) {
  __shared__ unsigned short hbuf[16384];   // 32KB, reused 3x

  const int t = threadIdx.x;
  const int bid = blockIdx.x;
  const int wrk = ((bid & 7) << 8) | (bid >> 3);   // XCD swizzle (2048%8==0)
  const int b = wrk >> 6;
  const int wid = t >> 6, lane = t & 63;
  const int q = lane & 15, g = lane >> 4;
  const int mo = wid << 6;

  // ---- phase 0: stage h1 = relu(U1[row] + V1c[wrk]) into hbuf ----
  {
    const int row = t >> 2, sl = t & 3, r7 = row & 7;
    const unsigned short* uB = U1 + (size_t)(b * 64 + row) * 256;
    const float* vB = V1c + (size_t)wrk * 256;
    unsigned short* hB = hbuf + row * 256;
#pragma unroll
    for (int m = 0; m < 8; ++m) {
      int ks = sl + 4 * m;                 // content k-slice (contiguous U read)
      int s = ks ^ r7;                     // swizzled slot
      short8 u = *(const short8*)(uB + ks * 8);
      f32x4 v0 = *(const f32x4*)(vB + ks * 8);
      f32x4 v1 = *(const f32x4*)(vB + ks * 8 + 4);
      write_h1(u, v0, v1, hB + s * 8);
    }
  }

  // A-fragment bases (1KB bursts per (wid,ch,mf))
  const unsigned short* aW2 = W2R + (size_t)wid * 16384 + lane * 8;
  const unsigned short* aW3 = W3R + (size_t)wid * 16384 + lane * 8;

  short8 a_[4], an_[4];
#pragma unroll
  for (int mf = 0; mf < 4; ++mf) a_[mf] = *(const short8*)(aW2 + mf * 512);

  __syncthreads();                         // [1] h1 complete

  f32x4 acc[4][4];
#pragma unroll
  for (int mf = 0; mf < 4; ++mf)
#pragma unroll
    for (int nf = 0; nf < 4; ++nf) acc[mf][nf] = (f32x4){0.f, 0.f, 0.f, 0.f};

  // ---- GEMM1: acc = G2^T * h1^T, 8 chunks, BARRIER-FREE ----
  for (int ch = 0; ch < 8; ++ch) {
    if (ch < 7) {
#pragma unroll
      for (int mf = 0; mf < 4; ++mf)
        an_[mf] = *(const short8*)(aW2 + (ch + 1) * 2048 + mf * 512);
    }
    short8 b_[4];
#pragma unroll
    for (int nf = 0; nf < 4; ++nf) {
      int r = q + 16 * nf;
      b_[nf] = *(const short8*)(hbuf + r * 256 + (((ch * 4 + g) ^ (r & 7)) * 8));
    }
#pragma unroll
    for (int mf = 0; mf < 4; ++mf)
#pragma unroll
      for (int nf = 0; nf < 4; ++nf)
        acc[mf][nf] = __builtin_amdgcn_mfma_f32_16x16x32_bf16(a_[mf], b_[nf], acc[mf][nf], 0, 0, 0);
    if (ch < 7) {
#pragma unroll
      for (int mf = 0; mf < 4; ++mf) a_[mf] = an_[mf];
    }
  }

  __syncthreads();                         // [2] all h1 reads done

  // ---- transition: h2 = relu(acc+b2) -> hbuf; prefetch W3 chunk 0 ----
#pragma unroll
  for (int mf = 0; mf < 4; ++mf) a_[mf] = *(const short8*)(aW3 + mf * 512);
#pragma unroll
  for (int mf = 0; mf < 4; ++mf) {
    int c2b = mo + 16 * mf + 4 * g;
    f32x4 bb = *(const f32x4*)(b2 + c2b);
    int ksw = c2b >> 3, off = c2b & 7;
#pragma unroll
    for (int nf = 0; nf < 4; ++nf) {
      int r = q + 16 * nf;
      f32x4 v = acc[mf][nf];
      float e0 = fmaxf(v.x + bb.x, 0.f), e1 = fmaxf(v.y + bb.y, 0.f);
      float e2 = fmaxf(v.z + bb.z, 0.f), e3 = fmaxf(v.w + bb.w, 0.f);
      i32x2 wv = { (int)pk2(e0, e1), (int)pk2(e2, e3) };
      *(i32x2*)(hbuf + r * 256 + ((ksw ^ (r & 7)) * 8) + off) = wv;
    }
  }
  __syncthreads();                         // [3] h2 complete

  // ---- GEMM2: acc2 = G3^T * h2^T, 8 chunks, BARRIER-FREE ----
  f32x4 acc2[4][4];
#pragma unroll
  for (int mf = 0; mf < 4; ++mf)
#pragma unroll
    for (int nf = 0; nf < 4; ++nf) acc2[mf][nf] = (f32x4){0.f, 0.f, 0.f, 0.f};

  for (int ch = 0; ch < 8; ++ch) {
    if (ch < 7) {
#pragma unroll
      for (int mf = 0; mf < 4; ++mf)
        an_[mf] = *(const short8*)(aW3 + (ch + 1) * 2048 + mf * 512);
    }
    short8 b_[4];
#pragma unroll
    for (int nf = 0; nf < 4; ++nf) {
      int r = q + 16 * nf;
      b_[nf] = *(const short8*)(hbuf + r * 256 + (((ch * 4 + g) ^ (r & 7)) * 8));
    }
#pragma unroll
    for (int mf = 0; mf < 4; ++mf)
#pragma unroll
      for (int nf = 0; nf < 4; ++nf)
        acc2[mf][nf] = __builtin_amdgcn_mfma_f32_16x16x32_bf16(a_[mf], b_[nf], acc2[mf][nf], 0, 0, 0);
    if (ch < 7) {
#pragma unroll
      for (int mf = 0; mf < 4; ++mf) a_[mf] = an_[mf];
    }
  }

  __syncthreads();                         // [4] all h2 reads done

  // ---- epilogue: h3 = relu(acc2+b3); row-sum via f32 LDS scratch ----
  float* scr = (float*)&hbuf[0];           // [16 q][264 pad] f32 = 16.9KB
#pragma unroll
  for (int mf = 0; mf < 4; ++mf) {
    int n3b = mo + 16 * mf + 4 * g;
    f32x4 bb = *(const f32x4*)(b3 + n3b);
    f32x4 sum = (f32x4){0.f, 0.f, 0.f, 0.f};
#pragma unroll
    for (int nf = 0; nf < 4; ++nf) {
      f32x4 v = acc2[mf][nf];
      sum.x += fmaxf(v.x + bb.x, 0.f);
      sum.y += fmaxf(v.y + bb.y, 0.f);
      sum.z += fmaxf(v.z + bb.z, 0.f);
      sum.w += fmaxf(v.w + bb.w, 0.f);
    }
    *(f32x4*)(scr + q * 264 + n3b) = sum;
  }
  __syncthreads();                         // [5] scratch complete
  float s = 0.f;
#pragma unroll
  for (int q2 = 0; q2 < 16; ++q2) s += scr[q2 * 264 + t];
  partials[(size_t)wrk * 256 + t] = s;
}

// ---------------------------------------------------------------------------
// Reduce partials per batch + f-MLP (f32). grid 32 x 256.
// ---------------------------------------------------------------------------
__global__ void k_fmlp(const float* __restrict__ partials,
                       const float* __restrict__ f1w, const float* __restrict__ f1b,
                       const float* __restrict__ f2w, const float* __restrict__ f2b,
                       const float* __restrict__ f3w, const float* __restrict__ f3b,
                       float* __restrict__ out) {
  const int b = blockIdx.x, t = threadIdx.x;
  __shared__ float xg[256], x1[256], x2[256];
  {
    const float* p = partials + (size_t)(b * 64) * 256 + t;
    float s[8];
#pragma unroll
    for (int i = 0; i < 8; ++i) s[i] = 0.f;
#pragma unroll
    for (int k = 0; k < 8; ++k)
#pragma unroll
      for (int i = 0; i < 8; ++i) s[i] += p[(k * 8 + i) * 256];
    float tot = 0.f;
#pragma unroll
    for (int i = 0; i < 8; ++i) tot += s[i];
    xg[t] = tot;
  }
  __syncthreads();
  {
    float a0 = 0.f, a1 = 0.f, a2 = 0.f, a3 = 0.f;
#pragma unroll 4
    for (int k = 0; k < 64; ++k) {
      a0 += xg[k]       * f1w[(k)       * 256 + t];
      a1 += xg[k + 64]  * f1w[(k + 64)  * 256 + t];
      a2 += xg[k + 128] * f1w[(k + 128) * 256 + t];
      a3 += xg[k + 192] * f1w[(k + 192) * 256 + t];
    }
    x1[t] = fmaxf((a0 + a1) + (a2 + a3) + f1b[t], 0.f);
  }
  __syncthreads();
  {
    float a0 = 0.f, a1 = 0.f, a2 = 0.f, a3 = 0.f;
#pragma unroll 4
    for (int k = 0; k < 64; ++k) {
      a0 += x1[k]       * f2w[(k)       * 256 + t];
      a1 += x1[k + 64]  * f2w[(k + 64)  * 256 + t];
      a2 += x1[k + 128] * f2w[(k + 128) * 256 + t];
      a3 += x1[k + 192] * f2w[(k + 192) * 256 + t];
    }
    x2[t] = fmaxf((a0 + a1) + (a2 + a3) + f2b[t], 0.f);
  }
  __syncthreads();
  if (t < 128) {
    float a0 = 0.f, a1 = 0.f, a2 = 0.f, a3 = 0.f;
#pragma unroll 4
    for (int k = 0; k < 64; ++k) {
      a0 += x2[k]       * f3w[(k)       * 128 + t];
      a1 += x2[k + 64]  * f3w[(k + 64)  * 128 + t];
      a2 += x2[k + 128] * f3w[(k + 128) * 128 + t];
      a3 += x2[k + 192] * f3w[(k + 192) * 128 + t];
    }
    out[b * 128 + t] = (a0 + a1) + (a2 + a3) + f3b[t];
  }
}

__global__ void k_zero(float* __restrict__ out, int n) {
  int i = blockIdx.x * 256 + threadIdx.x;
  if (i < n) out[i] = 0.f;
}

// ---------------------------------------------------------------------------
extern "C" void kernel_launch(void* const* d_in, const int* in_sizes, int n_in,
                              void* d_out, int out_size, void* d_ws, size_t ws_size,
                              hipStream_t stream) {
  const float* x      = (const float*)d_in[0];
  const float* edge_w = (const float*)d_in[1];
  const float* edge_b = (const float*)d_in[2];
  const float *gw0, *gw1, *gw2, *gb0, *gb1, *gb2;
  const float *f1w, *f1b, *f2w, *f2b, *f3w, *f3b;

  if (n_in >= 15 && in_sizes[3] == 65536 && in_sizes[4] == 65536 && in_sizes[5] == 65536) {
    gw0 = (const float*)d_in[3]; gw1 = (const float*)d_in[4]; gw2 = (const float*)d_in[5];
    gb0 = (const float*)d_in[6]; gb1 = (const float*)d_in[7]; gb2 = (const float*)d_in[8];
    f1w = (const float*)d_in[9];  f1b = (const float*)d_in[10];
    f2w = (const float*)d_in[11]; f2b = (const float*)d_in[12];
    f3w = (const float*)d_in[13]; f3b = (const float*)d_in[14];
  } else if (n_in >= 15 && in_sizes[3] == 65536 && in_sizes[4] == 256) {
    gw0 = (const float*)d_in[3]; gb0 = (const float*)d_in[4];
    gw1 = (const float*)d_in[5]; gb1 = (const float*)d_in[6];
    gw2 = (const float*)d_in[7]; gb2 = (const float*)d_in[8];
    f1w = (const float*)d_in[9];  f1b = (const float*)d_in[10];
    f2w = (const float*)d_in[11]; f2b = (const float*)d_in[12];
    f3w = (const float*)d_in[13]; f3b = (const float*)d_in[14];
  } else {
    const float* gws = (const float*)d_in[3];
    const float* gbs = (const float*)d_in[4];
    gw0 = gws;          gw1 = gws + 65536;  gw2 = gws + 131072;
    gb0 = gbs;          gb1 = gbs + 256;    gb2 = gbs + 512;
    f1w = (const float*)d_in[5];  f1b = (const float*)d_in[6];
    f2w = (const float*)d_in[7];  f2b = (const float*)d_in[8];
    f3w = (const float*)d_in[9];  f3b = (const float*)d_in[10];
  }

  char* ws = (char*)d_ws;
  float*          W1u      = (float*)(ws);                    // 256KB
  float*          W1v      = (float*)(ws + 262144);           // 256KB
  float*          c1       = (float*)(ws + 524288);           // 1KB
  unsigned short* W2R      = (unsigned short*)(ws + 525312);  // 128KB
  unsigned short* W3R      = (unsigned short*)(ws + 656384);  // 128KB
  unsigned short* U1       = (unsigned short*)(ws + 787456);  // 1MB   (bf16)
  float*          V1c      = (float*)(ws + 1836032);          // 2MB
  float*          partials = (float*)(ws + 3933184);          // 2MB
  const size_t need = 6030336;
  (void)out_size; (void)n_in;

  if (ws_size < need) {
    k_zero<<<dim3((out_size + 255) / 256), dim3(256), 0, stream>>>((float*)d_out, out_size);
    return;
  }

  k_prep<<<dim3(321), dim3(256), 0, stream>>>(edge_w, edge_b, gw0, gb0, gw1, gw2,
                                              W1u, W1v, c1, W2R, W3R);
  k_uv<<<dim3(256), dim3(1024), 0, stream>>>(x, W1u, W1v, c1, U1, V1c);
  k_main<<<dim3(2048), dim3(256), 0, stream>>>(U1, V1c, W2R, W3R, gb1, gb2, partials);
  k_fmlp<<<dim3(32), dim3(256), 0, stream>>>(partials, f1w, f1b, f2w, f2b, f3w, f3b,
                                             (float*)d_out);
}

// Round 7
// 76.038 us; speedup vs baseline: 1.8291x; 1.0426x over previous
//
#include <hip/hip_runtime.h>
#include <hip/hip_bf16.h>

typedef __attribute__((ext_vector_type(4))) float f32x4;
typedef __attribute__((ext_vector_type(2))) int   i32x2;
typedef __attribute__((ext_vector_type(4))) int   i32x4;
typedef __attribute__((ext_vector_type(8))) short short8;

__device__ __forceinline__ unsigned short f2bf(float x) {
  __hip_bfloat16 h = __float2bfloat16(x);
  union { __hip_bfloat16 h1; unsigned short u; } c; c.h1 = h; return c.u;
}
__device__ __forceinline__ unsigned pk2(float a, float b) {
  __hip_bfloat162 h = __float22bfloat162_rn(make_float2(a, b));
  union { __hip_bfloat162 h2; unsigned u; } c; c.h2 = h; return c.u;
}
__device__ __forceinline__ float bf2f(unsigned short u) {
  union { unsigned u32; float f; } c; c.u32 = ((unsigned)u) << 16; return c.f;
}

// ---------------------------------------------------------------------------
// Prep. grid 321 x 256:
//   blk<256   : W1u = edge_w[:256]@G1, W1v = edge_w[256:]@G1 (f32)
//   blk==256  : c1 = edge_b@G1 + gb0
//   blk 257.. : W2R/W3R = gw1/gw2 in MFMA-fragment-scheduled bf16 layout:
//               fragment (wave w, chunk ch, mf) is a contiguous 1KB burst.
// ---------------------------------------------------------------------------
__global__ void k_prep(const float* __restrict__ edge_w, const float* __restrict__ edge_b,
                       const float* __restrict__ gw0, const float* __restrict__ gb0,
                       const float* __restrict__ gw1, const float* __restrict__ gw2,
                       float* __restrict__ W1u, float* __restrict__ W1v,
                       float* __restrict__ c1,
                       unsigned short* __restrict__ W2R, unsigned short* __restrict__ W3R) {
  const int blk = blockIdx.x, t = threadIdx.x;
  __shared__ float eu[256], ev[256];
  if (blk < 256) {
    eu[t] = edge_w[blk * 256 + t];
    ev[t] = edge_w[(256 + blk) * 256 + t];
    __syncthreads();
    float su = 0.f, sv = 0.f;
    for (int o = 0; o < 256; ++o) {
      float gg = gw0[o * 256 + t];
      su += eu[o] * gg; sv += ev[o] * gg;
    }
    W1u[blk * 256 + t] = su;
    W1v[blk * 256 + t] = sv;
  } else if (blk == 256) {
    float s = gb0[t];
    for (int o = 0; o < 256; ++o) s += edge_b[o] * gw0[o * 256 + t];
    c1[t] = s;
  } else {
    int p = blk - 257;                       // 0..63: [0,32)->W2R, [32,64)->W3R
    const float* src = (p < 32) ? gw1 : gw2;
    unsigned short* dst = (p < 32) ? W2R : W3R;
    p &= 31;
    int w = p >> 3, ch = p & 7;
    int mf = t >> 6, lane = t & 63, q = lane & 15, g = lane >> 4;
    int base = ((w * 8 + ch) * 4 + mf) * 512 + lane * 8;
    int m = w * 64 + mf * 16 + q;
#pragma unroll
    for (int e = 0; e < 8; ++e) {
      int k = ch * 32 + g * 8 + e;
      dst[base + e] = f2bf(src[k * 256 + m]);
    }
  }
}

// ---------------------------------------------------------------------------
// Convert W1u/W1v (f32 [k][m]) -> W1uR/W1vR (bf16 fragment-scheduled).
// grid 64 x 256: blk<32 -> W1uR, else W1vR. Same transform as k_prep W2R branch.
// ---------------------------------------------------------------------------
__global__ void k_wcvt(const float* __restrict__ W1u, const float* __restrict__ W1v,
                       unsigned short* __restrict__ W1uR, unsigned short* __restrict__ W1vR) {
  int p = blockIdx.x;
  const float* src = (p < 32) ? W1u : W1v;
  unsigned short* dst = (p < 32) ? W1uR : W1vR;
  p &= 31;
  const int t = threadIdx.x;
  int w = p >> 3, ch = p & 7;
  int mf = t >> 6, lane = t & 63, q = lane & 15, g = lane >> 4;
  int base = ((w * 8 + ch) * 4 + mf) * 512 + lane * 8;
  int m = w * 64 + mf * 16 + q;
#pragma unroll
  for (int e = 0; e < 8; ++e) {
    int k = ch * 32 + g * 8 + e;
    dst[base + e] = f2bf(src[k * 256 + m]);
  }
}

// ---------------------------------------------------------------------------
// U1(bf16) = x @ W1u, V1c(f32) = x @ W1v + c1 — via MFMA.
// grid 128 x 256: tile = bid>>1 (32 rows), sel = bid&1 (0->U, 1->V).
// x staged bf16 into LDS (k_main swizzle family); W from fragment layout.
// ---------------------------------------------------------------------------
__global__ void k_uv(const float* __restrict__ x,
                     const unsigned short* __restrict__ W1uR,
                     const unsigned short* __restrict__ W1vR,
                     const float* __restrict__ c1,
                     unsigned short* __restrict__ U1, float* __restrict__ V1c) {
  __shared__ unsigned short xs[8192];       // [32 row][256 k] bf16, swizzled

  const int t = threadIdx.x;
  const int tile = blockIdx.x >> 1, sel = blockIdx.x & 1;
  const int r0 = tile * 32;
  const int wid = t >> 6, lane = t & 63;
  const int q = lane & 15, g = lane >> 4;
  const int mo = wid << 6;

  // stage x rows r0..r0+31 as bf16, element (r,k) at xs[r*256 + ((k>>3)^(r&7))*8 + (k&7)]
  {
    const int row = t >> 3, sl = t & 7, r7 = row & 7;
    const float* xB = x + (size_t)(r0 + row) * 256;
    unsigned short* hB = xs + row * 256;
#pragma unroll
    for (int m = 0; m < 4; ++m) {
      int ks = sl + 8 * m;
      f32x4 u0 = *(const f32x4*)(xB + ks * 8);
      f32x4 u1 = *(const f32x4*)(xB + ks * 8 + 4);
      i32x4 wv = { (int)pk2(u0.x, u0.y), (int)pk2(u0.z, u0.w),
                   (int)pk2(u1.x, u1.y), (int)pk2(u1.z, u1.w) };
      *(i32x4*)(hB + (ks ^ r7) * 8) = wv;
    }
  }

  const unsigned short* WR = sel ? W1vR : W1uR;
  const unsigned short* aW = WR + (size_t)wid * 16384 + lane * 8;

  short8 a_[4], an_[4];
#pragma unroll
  for (int mf = 0; mf < 4; ++mf) a_[mf] = *(const short8*)(aW + mf * 512);

  __syncthreads();

  f32x4 acc[4][2];
#pragma unroll
  for (int mf = 0; mf < 4; ++mf)
#pragma unroll
    for (int nf = 0; nf < 2; ++nf) acc[mf][nf] = (f32x4){0.f, 0.f, 0.f, 0.f};

  for (int ch = 0; ch < 8; ++ch) {
    if (ch < 7) {
#pragma unroll
      for (int mf = 0; mf < 4; ++mf)
        an_[mf] = *(const short8*)(aW + (ch + 1) * 2048 + mf * 512);
    }
    short8 b_[2];
#pragma unroll
    for (int nf = 0; nf < 2; ++nf) {
      int r = q + 16 * nf;
      b_[nf] = *(const short8*)(xs + r * 256 + (((ch * 4 + g) ^ (r & 7)) * 8));
    }
#pragma unroll
    for (int mf = 0; mf < 4; ++mf)
#pragma unroll
      for (int nf = 0; nf < 2; ++nf)
        acc[mf][nf] = __builtin_amdgcn_mfma_f32_16x16x32_bf16(a_[mf], b_[nf], acc[mf][nf], 0, 0, 0);
    if (ch < 7) {
#pragma unroll
      for (int mf = 0; mf < 4; ++mf) a_[mf] = an_[mf];
    }
  }

  // epilogue: C[feat][row] frag -> row-major outputs
#pragma unroll
  for (int mf = 0; mf < 4; ++mf) {
    int c2b = mo + 16 * mf + 4 * g;          // 4 consecutive features
#pragma unroll
    for (int nf = 0; nf < 2; ++nf) {
      int r = r0 + q + 16 * nf;
      f32x4 v = acc[mf][nf];
      if (sel == 0) {
        i32x2 wv = { (int)pk2(v.x, v.y), (int)pk2(v.z, v.w) };
        *(i32x2*)(U1 + (size_t)r * 256 + c2b) = wv;
      } else {
        f32x4 cc = *(const f32x4*)(c1 + c2b);
        f32x4 o = { v.x + cc.x, v.y + cc.y, v.z + cc.z, v.w + cc.w };
        *(f32x4*)(V1c + (size_t)r * 256 + c2b) = o;
      }
    }
  }
}

// ---------------------------------------------------------------------------
// Main fused kernel, 3-phase / 5-barrier (unchanged from R6).
// ---------------------------------------------------------------------------
__device__ __forceinline__ void write_h1(short8 u, f32x4 v0, f32x4 v1,
                                         unsigned short* dst) {
  float r0 = fmaxf(bf2f((unsigned short)u[0]) + v0.x, 0.f);
  float r1 = fmaxf(bf2f((unsigned short)u[1]) + v0.y, 0.f);
  float r2 = fmaxf(bf2f((unsigned short)u[2]) + v0.z, 0.f);
  float r3 = fmaxf(bf2f((unsigned short)u[3]) + v0.w, 0.f);
  float r4 = fmaxf(bf2f((unsigned short)u[4]) + v1.x, 0.f);
  float r5 = fmaxf(bf2f((unsigned short)u[5]) + v1.y, 0.f);
  float r6 = fmaxf(bf2f((unsigned short)u[6]) + v1.z, 0.f);
  float r7 = fmaxf(bf2f((unsigned short)u[7]) + v1.w, 0.f);
  i32x4 wv = { (int)pk2(r0, r1), (int)pk2(r2, r3), (int)pk2(r4, r5), (int)pk2(r6, r7) };
  *(i32x4*)dst = wv;
}

__launch_bounds__(256, 3)
__global__ void k_main(const unsigned short* __restrict__ U1,
                       const float* __restrict__ V1c,
                       const unsigned short* __restrict__ W2R,
                       const unsigned short* __restrict__ W3R,
                       const float* __restrict__ b2, const float* __restrict__ b3,
                       float* __restrict__ partials) {
  __shared__ unsigned short hbuf[16384];   // 32KB, reused 3x

  const int t = threadIdx.x;
  const int bid = blockIdx.x;
  const int wrk = ((bid & 7) << 8) | (bid >> 3);   // XCD swizzle (2048%8==0)
  const int b = wrk >> 6;
  const int wid = t >> 6, lane = t & 63;
  const int q = lane & 15, g = lane >> 4;
  const int mo = wid << 6;

  // ---- phase 0: stage h1 = relu(U1[row] + V1c[wrk]) into hbuf ----
  {
    const int row = t >> 2, sl = t & 3, r7 = row & 7;
    const unsigned short* uB = U1 + (size_t)(b * 64 + row) * 256;
    const float* vB = V1c + (size_t)wrk * 256;
    unsigned short* hB = hbuf + row * 256;
#pragma unroll
    for (int m = 0; m < 8; ++m) {
      int ks = sl + 4 * m;                 // content k-slice (contiguous U read)
      int s = ks ^ r7;                     // swizzled slot
      short8 u = *(const short8*)(uB + ks * 8);
      f32x4 v0 = *(const f32x4*)(vB + ks * 8);
      f32x4 v1 = *(const f32x4*)(vB + ks * 8 + 4);
      write_h1(u, v0, v1, hB + s * 8);
    }
  }

  const unsigned short* aW2 = W2R + (size_t)wid * 16384 + lane * 8;
  const unsigned short* aW3 = W3R + (size_t)wid * 16384 + lane * 8;

  short8 a_[4], an_[4];
#pragma unroll
  for (int mf = 0; mf < 4; ++mf) a_[mf] = *(const short8*)(aW2 + mf * 512);

  __syncthreads();                         // [1] h1 complete

  f32x4 acc[4][4];
#pragma unroll
  for (int mf = 0; mf < 4; ++mf)
#pragma unroll
    for (int nf = 0; nf < 4; ++nf) acc[mf][nf] = (f32x4){0.f, 0.f, 0.f, 0.f};

  // ---- GEMM1: acc = G2^T * h1^T, 8 chunks, BARRIER-FREE ----
  for (int ch = 0; ch < 8; ++ch) {
    if (ch < 7) {
#pragma unroll
      for (int mf = 0; mf < 4; ++mf)
        an_[mf] = *(const short8*)(aW2 + (ch + 1) * 2048 + mf * 512);
    }
    short8 b_[4];
#pragma unroll
    for (int nf = 0; nf < 4; ++nf) {
      int r = q + 16 * nf;
      b_[nf] = *(const short8*)(hbuf + r * 256 + (((ch * 4 + g) ^ (r & 7)) * 8));
    }
#pragma unroll
    for (int mf = 0; mf < 4; ++mf)
#pragma unroll
      for (int nf = 0; nf < 4; ++nf)
        acc[mf][nf] = __builtin_amdgcn_mfma_f32_16x16x32_bf16(a_[mf], b_[nf], acc[mf][nf], 0, 0, 0);
    if (ch < 7) {
#pragma unroll
      for (int mf = 0; mf < 4; ++mf) a_[mf] = an_[mf];
    }
  }

  __syncthreads();                         // [2] all h1 reads done

  // ---- transition: h2 = relu(acc+b2) -> hbuf; prefetch W3 chunk 0 ----
#pragma unroll
  for (int mf = 0; mf < 4; ++mf) a_[mf] = *(const short8*)(aW3 + mf * 512);
#pragma unroll
  for (int mf = 0; mf < 4; ++mf) {
    int c2b = mo + 16 * mf + 4 * g;
    f32x4 bb = *(const f32x4*)(b2 + c2b);
    int ksw = c2b >> 3, off = c2b & 7;
#pragma unroll
    for (int nf = 0; nf < 4; ++nf) {
      int r = q + 16 * nf;
      f32x4 v = acc[mf][nf];
      float e0 = fmaxf(v.x + bb.x, 0.f), e1 = fmaxf(v.y + bb.y, 0.f);
      float e2 = fmaxf(v.z + bb.z, 0.f), e3 = fmaxf(v.w + bb.w, 0.f);
      i32x2 wv = { (int)pk2(e0, e1), (int)pk2(e2, e3) };
      *(i32x2*)(hbuf + r * 256 + ((ksw ^ (r & 7)) * 8) + off) = wv;
    }
  }
  __syncthreads();                         // [3] h2 complete

  // ---- GEMM2: acc2 = G3^T * h2^T, 8 chunks, BARRIER-FREE ----
  f32x4 acc2[4][4];
#pragma unroll
  for (int mf = 0; mf < 4; ++mf)
#pragma unroll
    for (int nf = 0; nf < 4; ++nf) acc2[mf][nf] = (f32x4){0.f, 0.f, 0.f, 0.f};

  for (int ch = 0; ch < 8; ++ch) {
    if (ch < 7) {
#pragma unroll
      for (int mf = 0; mf < 4; ++mf)
        an_[mf] = *(const short8*)(aW3 + (ch + 1) * 2048 + mf * 512);
    }
    short8 b_[4];
#pragma unroll
    for (int nf = 0; nf < 4; ++nf) {
      int r = q + 16 * nf;
      b_[nf] = *(const short8*)(hbuf + r * 256 + (((ch * 4 + g) ^ (r & 7)) * 8));
    }
#pragma unroll
    for (int mf = 0; mf < 4; ++mf)
#pragma unroll
      for (int nf = 0; nf < 4; ++nf)
        acc2[mf][nf] = __builtin_amdgcn_mfma_f32_16x16x32_bf16(a_[mf], b_[nf], acc2[mf][nf], 0, 0, 0);
    if (ch < 7) {
#pragma unroll
      for (int mf = 0; mf < 4; ++mf) a_[mf] = an_[mf];
    }
  }

  __syncthreads();                         // [4] all h2 reads done

  // ---- epilogue: h3 = relu(acc2+b3); row-sum via f32 LDS scratch ----
  float* scr = (float*)&hbuf[0];           // [16 q][264 pad] f32 = 16.9KB
#pragma unroll
  for (int mf = 0; mf < 4; ++mf) {
    int n3b = mo + 16 * mf + 4 * g;
    f32x4 bb = *(const f32x4*)(b3 + n3b);
    f32x4 sum = (f32x4){0.f, 0.f, 0.f, 0.f};
#pragma unroll
    for (int nf = 0; nf < 4; ++nf) {
      f32x4 v = acc2[mf][nf];
      sum.x += fmaxf(v.x + bb.x, 0.f);
      sum.y += fmaxf(v.y + bb.y, 0.f);
      sum.z += fmaxf(v.z + bb.z, 0.f);
      sum.w += fmaxf(v.w + bb.w, 0.f);
    }
    *(f32x4*)(scr + q * 264 + n3b) = sum;
  }
  __syncthreads();                         // [5] scratch complete
  float s = 0.f;
#pragma unroll
  for (int q2 = 0; q2 < 16; ++q2) s += scr[q2 * 264 + t];
  partials[(size_t)wrk * 256 + t] = s;
}

// ---------------------------------------------------------------------------
// Reduce partials per batch + f-MLP (f32). grid 32 x 256.
// ---------------------------------------------------------------------------
__global__ void k_fmlp(const float* __restrict__ partials,
                       const float* __restrict__ f1w, const float* __restrict__ f1b,
                       const float* __restrict__ f2w, const float* __restrict__ f2b,
                       const float* __restrict__ f3w, const float* __restrict__ f3b,
                       float* __restrict__ out) {
  const int b = blockIdx.x, t = threadIdx.x;
  __shared__ float xg[256], x1[256], x2[256];
  {
    const float* p = partials + (size_t)(b * 64) * 256 + t;
    float s[8];
#pragma unroll
    for (int i = 0; i < 8; ++i) s[i] = 0.f;
#pragma unroll
    for (int k = 0; k < 8; ++k)
#pragma unroll
      for (int i = 0; i < 8; ++i) s[i] += p[(k * 8 + i) * 256];
    float tot = 0.f;
#pragma unroll
    for (int i = 0; i < 8; ++i) tot += s[i];
    xg[t] = tot;
  }
  __syncthreads();
  {
    float a0 = 0.f, a1 = 0.f, a2 = 0.f, a3 = 0.f;
#pragma unroll 4
    for (int k = 0; k < 64; ++k) {
      a0 += xg[k]       * f1w[(k)       * 256 + t];
      a1 += xg[k + 64]  * f1w[(k + 64)  * 256 + t];
      a2 += xg[k + 128] * f1w[(k + 128) * 256 + t];
      a3 += xg[k + 192] * f1w[(k + 192) * 256 + t];
    }
    x1[t] = fmaxf((a0 + a1) + (a2 + a3) + f1b[t], 0.f);
  }
  __syncthreads();
  {
    float a0 = 0.f, a1 = 0.f, a2 = 0.f, a3 = 0.f;
#pragma unroll 4
    for (int k = 0; k < 64; ++k) {
      a0 += x1[k]       * f2w[(k)       * 256 + t];
      a1 += x1[k + 64]  * f2w[(k + 64)  * 256 + t];
      a2 += x1[k + 128] * f2w[(k + 128) * 256 + t];
      a3 += x1[k + 192] * f2w[(k + 192) * 256 + t];
    }
    x2[t] = fmaxf((a0 + a1) + (a2 + a3) + f2b[t], 0.f);
  }
  __syncthreads();
  if (t < 128) {
    float a0 = 0.f, a1 = 0.f, a2 = 0.f, a3 = 0.f;
#pragma unroll 4
    for (int k = 0; k < 64; ++k) {
      a0 += x2[k]       * f3w[(k)       * 128 + t];
      a1 += x2[k + 64]  * f3w[(k + 64)  * 128 + t];
      a2 += x2[k + 128] * f3w[(k + 128) * 128 + t];
      a3 += x2[k + 192] * f3w[(k + 192) * 128 + t];
    }
    out[b * 128 + t] = (a0 + a1) + (a2 + a3) + f3b[t];
  }
}

__global__ void k_zero(float* __restrict__ out, int n) {
  int i = blockIdx.x * 256 + threadIdx.x;
  if (i < n) out[i] = 0.f;
}

// ---------------------------------------------------------------------------
extern "C" void kernel_launch(void* const* d_in, const int* in_sizes, int n_in,
                              void* d_out, int out_size, void* d_ws, size_t ws_size,
                              hipStream_t stream) {
  const float* x      = (const float*)d_in[0];
  const float* edge_w = (const float*)d_in[1];
  const float* edge_b = (const float*)d_in[2];
  const float *gw0, *gw1, *gw2, *gb0, *gb1, *gb2;
  const float *f1w, *f1b, *f2w, *f2b, *f3w, *f3b;

  if (n_in >= 15 && in_sizes[3] == 65536 && in_sizes[4] == 65536 && in_sizes[5] == 65536) {
    gw0 = (const float*)d_in[3]; gw1 = (const float*)d_in[4]; gw2 = (const float*)d_in[5];
    gb0 = (const float*)d_in[6]; gb1 = (const float*)d_in[7]; gb2 = (const float*)d_in[8];
    f1w = (const float*)d_in[9];  f1b = (const float*)d_in[10];
    f2w = (const float*)d_in[11]; f2b = (const float*)d_in[12];
    f3w = (const float*)d_in[13]; f3b = (const float*)d_in[14];
  } else if (n_in >= 15 && in_sizes[3] == 65536 && in_sizes[4] == 256) {
    gw0 = (const float*)d_in[3]; gb0 = (const float*)d_in[4];
    gw1 = (const float*)d_in[5]; gb1 = (const float*)d_in[6];
    gw2 = (const float*)d_in[7]; gb2 = (const float*)d_in[8];
    f1w = (const float*)d_in[9];  f1b = (const float*)d_in[10];
    f2w = (const float*)d_in[11]; f2b = (const float*)d_in[12];
    f3w = (const float*)d_in[13]; f3b = (const float*)d_in[14];
  } else {
    const float* gws = (const float*)d_in[3];
    const float* gbs = (const float*)d_in[4];
    gw0 = gws;          gw1 = gws + 65536;  gw2 = gws + 131072;
    gb0 = gbs;          gb1 = gbs + 256;    gb2 = gbs + 512;
    f1w = (const float*)d_in[5];  f1b = (const float*)d_in[6];
    f2w = (const float*)d_in[7];  f2b = (const float*)d_in[8];
    f3w = (const float*)d_in[9];  f3b = (const float*)d_in[10];
  }

  char* ws = (char*)d_ws;
  float*          W1u      = (float*)(ws);                    // 256KB
  float*          W1v      = (float*)(ws + 262144);           // 256KB
  float*          c1       = (float*)(ws + 524288);           // 1KB
  unsigned short* W2R      = (unsigned short*)(ws + 525312);  // 128KB
  unsigned short* W3R      = (unsigned short*)(ws + 656384);  // 128KB
  unsigned short* U1       = (unsigned short*)(ws + 787456);  // 1MB   (bf16)
  float*          V1c      = (float*)(ws + 1836032);          // 2MB
  float*          partials = (float*)(ws + 3933184);          // 2MB
  // W1uR/W1vR alias the partials region (dead until k_main writes it):
  unsigned short* W1uR     = (unsigned short*)(ws + 3933184);           // 128KB
  unsigned short* W1vR     = (unsigned short*)(ws + 3933184 + 131072);  // 128KB
  const size_t need = 6030336;
  (void)out_size; (void)n_in;

  if (ws_size < need) {
    k_zero<<<dim3((out_size + 255) / 256), dim3(256), 0, stream>>>((float*)d_out, out_size);
    return;
  }

  k_prep<<<dim3(321), dim3(256), 0, stream>>>(edge_w, edge_b, gw0, gb0, gw1, gw2,
                                              W1u, W1v, c1, W2R, W3R);
  k_wcvt<<<dim3(64), dim3(256), 0, stream>>>(W1u, W1v, W1uR, W1vR);
  k_uv<<<dim3(128), dim3(256), 0, stream>>>(x, W1uR, W1vR, c1, U1, V1c);
  k_main<<<dim3(2048), dim3(256), 0, stream>>>(U1, V1c, W2R, W3R, gb1, gb2, partials);
  k_fmlp<<<dim3(32), dim3(256), 0, stream>>>(partials, f1w, f1b, f2w, f2b, f3w, f3b,
                                             (float*)d_out);
}

// Round 8
// 71.726 us; speedup vs baseline: 1.9390x; 1.0601x over previous
//
#include <hip/hip_runtime.h>
#include <hip/hip_bf16.h>

typedef __attribute__((ext_vector_type(4))) float f32x4;
typedef __attribute__((ext_vector_type(2))) int   i32x2;
typedef __attribute__((ext_vector_type(4))) int   i32x4;
typedef __attribute__((ext_vector_type(8))) short short8;

__device__ __forceinline__ unsigned short f2bf(float x) {
  __hip_bfloat16 h = __float2bfloat16(x);
  union { __hip_bfloat16 h1; unsigned short u; } c; c.h1 = h; return c.u;
}
__device__ __forceinline__ unsigned pk2(float a, float b) {
  __hip_bfloat162 h = __float22bfloat162_rn(make_float2(a, b));
  union { __hip_bfloat162 h2; unsigned u; } c; c.h2 = h; return c.u;
}
__device__ __forceinline__ float bf2f(unsigned short u) {
  union { unsigned u32; float f; } c; c.u32 = ((unsigned)u) << 16; return c.f;
}

// ---------------------------------------------------------------------------
// Prep. grid 321 x 256:
//   blk<256   : row k=blk of W1u/W1v = edge_w@G1, written DIRECTLY to the
//               bf16 fragment-scheduled layouts W1uR/W1vR (k_wcvt fused).
//   blk==256  : c1 = edge_b@G1 + gb0
//   blk 257.. : W2R/W3R = gw1/gw2 fragment-scheduled bf16
//               (fragment (wave w, chunk ch, mf) = contiguous 1KB burst).
// ---------------------------------------------------------------------------
__global__ void k_prep(const float* __restrict__ edge_w, const float* __restrict__ edge_b,
                       const float* __restrict__ gw0, const float* __restrict__ gb0,
                       const float* __restrict__ gw1, const float* __restrict__ gw2,
                       unsigned short* __restrict__ W1uR, unsigned short* __restrict__ W1vR,
                       float* __restrict__ c1,
                       unsigned short* __restrict__ W2R, unsigned short* __restrict__ W3R) {
  const int blk = blockIdx.x, t = threadIdx.x;
  __shared__ float eu[256], ev[256];
  if (blk < 256) {
    eu[t] = edge_w[blk * 256 + t];
    ev[t] = edge_w[(256 + blk) * 256 + t];
    __syncthreads();
    float su = 0.f, sv = 0.f;
    for (int o = 0; o < 256; ++o) {
      float gg = gw0[o * 256 + t];
      su += eu[o] * gg; sv += ev[o] * gg;
    }
    // scatter (k=blk, m=t) into fragment layout
    const int k = blk, m = t;
    const int w = m >> 6, mf = (m >> 4) & 3, q = m & 15;
    const int ch = k >> 5, g = (k >> 3) & 3, e = k & 7;
    const int idx = ((w * 8 + ch) * 4 + mf) * 512 + (g * 16 + q) * 8 + e;
    W1uR[idx] = f2bf(su);
    W1vR[idx] = f2bf(sv);
  } else if (blk == 256) {
    float s = gb0[t];
    for (int o = 0; o < 256; ++o) s += edge_b[o] * gw0[o * 256 + t];
    c1[t] = s;
  } else {
    int p = blk - 257;                       // 0..63: [0,32)->W2R, [32,64)->W3R
    const float* src = (p < 32) ? gw1 : gw2;
    unsigned short* dst = (p < 32) ? W2R : W3R;
    p &= 31;
    int w = p >> 3, ch = p & 7;
    int mf = t >> 6, lane = t & 63, q = lane & 15, g = lane >> 4;
    int base = ((w * 8 + ch) * 4 + mf) * 512 + lane * 8;
    int m = w * 64 + mf * 16 + q;
#pragma unroll
    for (int e = 0; e < 8; ++e) {
      int k = ch * 32 + g * 8 + e;
      dst[base + e] = f2bf(src[k * 256 + m]);
    }
  }
}

// ---------------------------------------------------------------------------
// U1(bf16) = x @ W1u, V1c(f32) = x @ W1v + c1 — via MFMA (unchanged from R7).
// grid 128 x 256: tile = bid>>1 (32 rows), sel = bid&1 (0->U, 1->V).
// ---------------------------------------------------------------------------
__global__ void k_uv(const float* __restrict__ x,
                     const unsigned short* __restrict__ W1uR,
                     const unsigned short* __restrict__ W1vR,
                     const float* __restrict__ c1,
                     unsigned short* __restrict__ U1, float* __restrict__ V1c) {
  __shared__ unsigned short xs[8192];       // [32 row][256 k] bf16, swizzled

  const int t = threadIdx.x;
  const int tile = blockIdx.x >> 1, sel = blockIdx.x & 1;
  const int r0 = tile * 32;
  const int wid = t >> 6, lane = t & 63;
  const int q = lane & 15, g = lane >> 4;
  const int mo = wid << 6;

  {
    const int row = t >> 3, sl = t & 7, r7 = row & 7;
    const float* xB = x + (size_t)(r0 + row) * 256;
    unsigned short* hB = xs + row * 256;
#pragma unroll
    for (int m = 0; m < 4; ++m) {
      int ks = sl + 8 * m;
      f32x4 u0 = *(const f32x4*)(xB + ks * 8);
      f32x4 u1 = *(const f32x4*)(xB + ks * 8 + 4);
      i32x4 wv = { (int)pk2(u0.x, u0.y), (int)pk2(u0.z, u0.w),
                   (int)pk2(u1.x, u1.y), (int)pk2(u1.z, u1.w) };
      *(i32x4*)(hB + (ks ^ r7) * 8) = wv;
    }
  }

  const unsigned short* WR = sel ? W1vR : W1uR;
  const unsigned short* aW = WR + (size_t)wid * 16384 + lane * 8;

  short8 a_[4], an_[4];
#pragma unroll
  for (int mf = 0; mf < 4; ++mf) a_[mf] = *(const short8*)(aW + mf * 512);

  __syncthreads();

  f32x4 acc[4][2];
#pragma unroll
  for (int mf = 0; mf < 4; ++mf)
#pragma unroll
    for (int nf = 0; nf < 2; ++nf) acc[mf][nf] = (f32x4){0.f, 0.f, 0.f, 0.f};

  for (int ch = 0; ch < 8; ++ch) {
    if (ch < 7) {
#pragma unroll
      for (int mf = 0; mf < 4; ++mf)
        an_[mf] = *(const short8*)(aW + (ch + 1) * 2048 + mf * 512);
    }
    short8 b_[2];
#pragma unroll
    for (int nf = 0; nf < 2; ++nf) {
      int r = q + 16 * nf;
      b_[nf] = *(const short8*)(xs + r * 256 + (((ch * 4 + g) ^ (r & 7)) * 8));
    }
#pragma unroll
    for (int mf = 0; mf < 4; ++mf)
#pragma unroll
      for (int nf = 0; nf < 2; ++nf)
        acc[mf][nf] = __builtin_amdgcn_mfma_f32_16x16x32_bf16(a_[mf], b_[nf], acc[mf][nf], 0, 0, 0);
    if (ch < 7) {
#pragma unroll
      for (int mf = 0; mf < 4; ++mf) a_[mf] = an_[mf];
    }
  }

#pragma unroll
  for (int mf = 0; mf < 4; ++mf) {
    int c2b = mo + 16 * mf + 4 * g;
#pragma unroll
    for (int nf = 0; nf < 2; ++nf) {
      int r = r0 + q + 16 * nf;
      f32x4 v = acc[mf][nf];
      if (sel == 0) {
        i32x2 wv = { (int)pk2(v.x, v.y), (int)pk2(v.z, v.w) };
        *(i32x2*)(U1 + (size_t)r * 256 + c2b) = wv;
      } else {
        f32x4 cc = *(const f32x4*)(c1 + c2b);
        f32x4 o = { v.x + cc.x, v.y + cc.y, v.z + cc.z, v.w + cc.w };
        *(f32x4*)(V1c + (size_t)r * 256 + c2b) = o;
      }
    }
  }
}

// ---------------------------------------------------------------------------
// Main fused kernel — TWO itiles per block (halves W L2 traffic).
// grid 1024: block (b, ipair) -> itiles {2*ipair, 2*ipair+1}, 64 pair-rows each.
// LDS: bufA/bufB 32KB each (h1 -> h2 -> f32 scratch). 2 blocks/CU.
// Per chunk: 4 W-frag loads + 8 ds_reads feed 32 MFMA.
// ---------------------------------------------------------------------------
__device__ __forceinline__ void write_h1(short8 u, f32x4 v0, f32x4 v1,
                                         unsigned short* dst) {
  float r0 = fmaxf(bf2f((unsigned short)u[0]) + v0.x, 0.f);
  float r1 = fmaxf(bf2f((unsigned short)u[1]) + v0.y, 0.f);
  float r2 = fmaxf(bf2f((unsigned short)u[2]) + v0.z, 0.f);
  float r3 = fmaxf(bf2f((unsigned short)u[3]) + v0.w, 0.f);
  float r4 = fmaxf(bf2f((unsigned short)u[4]) + v1.x, 0.f);
  float r5 = fmaxf(bf2f((unsigned short)u[5]) + v1.y, 0.f);
  float r6 = fmaxf(bf2f((unsigned short)u[6]) + v1.z, 0.f);
  float r7 = fmaxf(bf2f((unsigned short)u[7]) + v1.w, 0.f);
  i32x4 wv = { (int)pk2(r0, r1), (int)pk2(r2, r3), (int)pk2(r4, r5), (int)pk2(r6, r7) };
  *(i32x4*)dst = wv;
}

__launch_bounds__(256, 2)
__global__ void k_main(const unsigned short* __restrict__ U1,
                       const float* __restrict__ V1c,
                       const unsigned short* __restrict__ W2R,
                       const unsigned short* __restrict__ W3R,
                       const float* __restrict__ b2, const float* __restrict__ b3,
                       float* __restrict__ partials) {
  __shared__ unsigned short bufA[16384];   // 32KB, reused 3x
  __shared__ unsigned short bufB[16384];   // 32KB, reused 3x

  const int t = threadIdx.x;
  const int bid = blockIdx.x;
  const int wrk = ((bid & 7) << 7) | (bid >> 3);   // XCD swizzle (1024%8==0)
  const int b = wrk >> 5;
  const int it0 = (wrk & 31) * 2;
  const int wid = t >> 6, lane = t & 63;
  const int q = lane & 15, g = lane >> 4;
  const int mo = wid << 6;

  // ---- phase 0: stage h1_A / h1_B (shared U row, two V rows) ----
  {
    const int row = t >> 2, sl = t & 3, r7 = row & 7;
    const unsigned short* uB = U1 + (size_t)(b * 64 + row) * 256;
    const float* vA = V1c + (size_t)(b * 64 + it0) * 256;
    const float* vB = vA + 256;
    unsigned short* dA = bufA + row * 256;
    unsigned short* dB = bufB + row * 256;
#pragma unroll
    for (int m = 0; m < 8; ++m) {
      int ks = sl + 4 * m;
      int s8 = (ks ^ r7) * 8;
      short8 u = *(const short8*)(uB + ks * 8);
      f32x4 a0 = *(const f32x4*)(vA + ks * 8);
      f32x4 a1 = *(const f32x4*)(vA + ks * 8 + 4);
      f32x4 b0 = *(const f32x4*)(vB + ks * 8);
      f32x4 b1 = *(const f32x4*)(vB + ks * 8 + 4);
      write_h1(u, a0, a1, dA + s8);
      write_h1(u, b0, b1, dB + s8);
    }
  }

  const unsigned short* aW2 = W2R + (size_t)wid * 16384 + lane * 8;
  const unsigned short* aW3 = W3R + (size_t)wid * 16384 + lane * 8;

  short8 a_[4], an_[4];
#pragma unroll
  for (int mf = 0; mf < 4; ++mf) a_[mf] = *(const short8*)(aW2 + mf * 512);

  __syncthreads();                         // [1] h1 complete

  f32x4 accA[4][4], accB[4][4];
#pragma unroll
  for (int mf = 0; mf < 4; ++mf)
#pragma unroll
    for (int nf = 0; nf < 4; ++nf) {
      accA[mf][nf] = (f32x4){0.f, 0.f, 0.f, 0.f};
      accB[mf][nf] = (f32x4){0.f, 0.f, 0.f, 0.f};
    }

  // ---- GEMM1: acc{A,B} = G2^T * h1{A,B}^T, 8 chunks, barrier-free ----
  for (int ch = 0; ch < 8; ++ch) {
    if (ch < 7) {
#pragma unroll
      for (int mf = 0; mf < 4; ++mf)
        an_[mf] = *(const short8*)(aW2 + (ch + 1) * 2048 + mf * 512);
    }
    short8 bA[4], bB[4];
#pragma unroll
    for (int nf = 0; nf < 4; ++nf) {
      int r = q + 16 * nf;
      int off = r * 256 + (((ch * 4 + g) ^ (r & 7)) * 8);
      bA[nf] = *(const short8*)(bufA + off);
      bB[nf] = *(const short8*)(bufB + off);
    }
#pragma unroll
    for (int mf = 0; mf < 4; ++mf)
#pragma unroll
      for (int nf = 0; nf < 4; ++nf) {
        accA[mf][nf] = __builtin_amdgcn_mfma_f32_16x16x32_bf16(a_[mf], bA[nf], accA[mf][nf], 0, 0, 0);
        accB[mf][nf] = __builtin_amdgcn_mfma_f32_16x16x32_bf16(a_[mf], bB[nf], accB[mf][nf], 0, 0, 0);
      }
    if (ch < 7) {
#pragma unroll
      for (int mf = 0; mf < 4; ++mf) a_[mf] = an_[mf];
    }
  }

  __syncthreads();                         // [2] all h1 reads done

  // ---- transition: h2{A,B} = relu(acc{A,B}+b2) -> buf{A,B}; prefetch W3 ----
#pragma unroll
  for (int mf = 0; mf < 4; ++mf) a_[mf] = *(const short8*)(aW3 + mf * 512);
#pragma unroll
  for (int mf = 0; mf < 4; ++mf) {
    int c2b = mo + 16 * mf + 4 * g;
    f32x4 bb = *(const f32x4*)(b2 + c2b);
    int ksw = c2b >> 3, off = c2b & 7;
#pragma unroll
    for (int nf = 0; nf < 4; ++nf) {
      int r = q + 16 * nf;
      int dst = r * 256 + ((ksw ^ (r & 7)) * 8) + off;
      f32x4 vA_ = accA[mf][nf];
      f32x4 vB_ = accB[mf][nf];
      i32x2 wA = { (int)pk2(fmaxf(vA_.x + bb.x, 0.f), fmaxf(vA_.y + bb.y, 0.f)),
                   (int)pk2(fmaxf(vA_.z + bb.z, 0.f), fmaxf(vA_.w + bb.w, 0.f)) };
      i32x2 wB = { (int)pk2(fmaxf(vB_.x + bb.x, 0.f), fmaxf(vB_.y + bb.y, 0.f)),
                   (int)pk2(fmaxf(vB_.z + bb.z, 0.f), fmaxf(vB_.w + bb.w, 0.f)) };
      *(i32x2*)(bufA + dst) = wA;
      *(i32x2*)(bufB + dst) = wB;
    }
  }
  __syncthreads();                         // [3] h2 complete

  // ---- GEMM2: reuse acc{A,B} as acc2, barrier-free ----
#pragma unroll
  for (int mf = 0; mf < 4; ++mf)
#pragma unroll
    for (int nf = 0; nf < 4; ++nf) {
      accA[mf][nf] = (f32x4){0.f, 0.f, 0.f, 0.f};
      accB[mf][nf] = (f32x4){0.f, 0.f, 0.f, 0.f};
    }

  for (int ch = 0; ch < 8; ++ch) {
    if (ch < 7) {
#pragma unroll
      for (int mf = 0; mf < 4; ++mf)
        an_[mf] = *(const short8*)(aW3 + (ch + 1) * 2048 + mf * 512);
    }
    short8 bA[4], bB[4];
#pragma unroll
    for (int nf = 0; nf < 4; ++nf) {
      int r = q + 16 * nf;
      int off = r * 256 + (((ch * 4 + g) ^ (r & 7)) * 8);
      bA[nf] = *(const short8*)(bufA + off);
      bB[nf] = *(const short8*)(bufB + off);
    }
#pragma unroll
    for (int mf = 0; mf < 4; ++mf)
#pragma unroll
      for (int nf = 0; nf < 4; ++nf) {
        accA[mf][nf] = __builtin_amdgcn_mfma_f32_16x16x32_bf16(a_[mf], bA[nf], accA[mf][nf], 0, 0, 0);
        accB[mf][nf] = __builtin_amdgcn_mfma_f32_16x16x32_bf16(a_[mf], bB[nf], accB[mf][nf], 0, 0, 0);
      }
    if (ch < 7) {
#pragma unroll
      for (int mf = 0; mf < 4; ++mf) a_[mf] = an_[mf];
    }
  }

  __syncthreads();                         // [4] all h2 reads done

  // ---- epilogue: h3 = relu(acc2+b3); row-sums via f32 LDS scratch ----
  float* scrA = (float*)&bufA[0];          // [16 q][264 pad] f32
  float* scrB = (float*)&bufB[0];
#pragma unroll
  for (int mf = 0; mf < 4; ++mf) {
    int n3b = mo + 16 * mf + 4 * g;
    f32x4 bb = *(const f32x4*)(b3 + n3b);
    f32x4 sA = (f32x4){0.f, 0.f, 0.f, 0.f};
    f32x4 sB = (f32x4){0.f, 0.f, 0.f, 0.f};
#pragma unroll
    for (int nf = 0; nf < 4; ++nf) {
      f32x4 vA_ = accA[mf][nf];
      f32x4 vB_ = accB[mf][nf];
      sA.x += fmaxf(vA_.x + bb.x, 0.f); sA.y += fmaxf(vA_.y + bb.y, 0.f);
      sA.z += fmaxf(vA_.z + bb.z, 0.f); sA.w += fmaxf(vA_.w + bb.w, 0.f);
      sB.x += fmaxf(vB_.x + bb.x, 0.f); sB.y += fmaxf(vB_.y + bb.y, 0.f);
      sB.z += fmaxf(vB_.z + bb.z, 0.f); sB.w += fmaxf(vB_.w + bb.w, 0.f);
    }
    *(f32x4*)(scrA + q * 264 + n3b) = sA;
    *(f32x4*)(scrB + q * 264 + n3b) = sB;
  }
  __syncthreads();                         // [5] scratch complete
  float sA = 0.f, sB = 0.f;
#pragma unroll
  for (int q2 = 0; q2 < 16; ++q2) {
    sA += scrA[q2 * 264 + t];
    sB += scrB[q2 * 264 + t];
  }
  partials[(size_t)(b * 64 + it0) * 256 + t] = sA;
  partials[(size_t)(b * 64 + it0 + 1) * 256 + t] = sB;
}

// ---------------------------------------------------------------------------
// Reduce partials per batch + f-MLP (f32). grid 32 x 256.
// ---------------------------------------------------------------------------
__global__ void k_fmlp(const float* __restrict__ partials,
                       const float* __restrict__ f1w, const float* __restrict__ f1b,
                       const float* __restrict__ f2w, const float* __restrict__ f2b,
                       const float* __restrict__ f3w, const float* __restrict__ f3b,
                       float* __restrict__ out) {
  const int b = blockIdx.x, t = threadIdx.x;
  __shared__ float xg[256], x1[256], x2[256];
  {
    const float* p = partials + (size_t)(b * 64) * 256 + t;
    float s[8];
#pragma unroll
    for (int i = 0; i < 8; ++i) s[i] = 0.f;
#pragma unroll
    for (int k = 0; k < 8; ++k)
#pragma unroll
      for (int i = 0; i < 8; ++i) s[i] += p[(k * 8 + i) * 256];
    float tot = 0.f;
#pragma unroll
    for (int i = 0; i < 8; ++i) tot += s[i];
    xg[t] = tot;
  }
  __syncthreads();
  {
    float a0 = 0.f, a1 = 0.f, a2 = 0.f, a3 = 0.f;
#pragma unroll 4
    for (int k = 0; k < 64; ++k) {
      a0 += xg[k]       * f1w[(k)       * 256 + t];
      a1 += xg[k + 64]  * f1w[(k + 64)  * 256 + t];
      a2 += xg[k + 128] * f1w[(k + 128) * 256 + t];
      a3 += xg[k + 192] * f1w[(k + 192) * 256 + t];
    }
    x1[t] = fmaxf((a0 + a1) + (a2 + a3) + f1b[t], 0.f);
  }
  __syncthreads();
  {
    float a0 = 0.f, a1 = 0.f, a2 = 0.f, a3 = 0.f;
#pragma unroll 4
    for (int k = 0; k < 64; ++k) {
      a0 += x1[k]       * f2w[(k)       * 256 + t];
      a1 += x1[k + 64]  * f2w[(k + 64)  * 256 + t];
      a2 += x1[k + 128] * f2w[(k + 128) * 256 + t];
      a3 += x1[k + 192] * f2w[(k + 192) * 256 + t];
    }
    x2[t] = fmaxf((a0 + a1) + (a2 + a3) + f2b[t], 0.f);
  }
  __syncthreads();
  if (t < 128) {
    float a0 = 0.f, a1 = 0.f, a2 = 0.f, a3 = 0.f;
#pragma unroll 4
    for (int k = 0; k < 64; ++k) {
      a0 += x2[k]       * f3w[(k)       * 128 + t];
      a1 += x2[k + 64]  * f3w[(k + 64)  * 128 + t];
      a2 += x2[k + 128] * f3w[(k + 128) * 128 + t];
      a3 += x2[k + 192] * f3w[(k + 192) * 128 + t];
    }
    out[b * 128 + t] = (a0 + a1) + (a2 + a3) + f3b[t];
  }
}

__global__ void k_zero(float* __restrict__ out, int n) {
  int i = blockIdx.x * 256 + threadIdx.x;
  if (i < n) out[i] = 0.f;
}

// ---------------------------------------------------------------------------
extern "C" void kernel_launch(void* const* d_in, const int* in_sizes, int n_in,
                              void* d_out, int out_size, void* d_ws, size_t ws_size,
                              hipStream_t stream) {
  const float* x      = (const float*)d_in[0];
  const float* edge_w = (const float*)d_in[1];
  const float* edge_b = (const float*)d_in[2];
  const float *gw0, *gw1, *gw2, *gb0, *gb1, *gb2;
  const float *f1w, *f1b, *f2w, *f2b, *f3w, *f3b;

  if (n_in >= 15 && in_sizes[3] == 65536 && in_sizes[4] == 65536 && in_sizes[5] == 65536) {
    gw0 = (const float*)d_in[3]; gw1 = (const float*)d_in[4]; gw2 = (const float*)d_in[5];
    gb0 = (const float*)d_in[6]; gb1 = (const float*)d_in[7]; gb2 = (const float*)d_in[8];
    f1w = (const float*)d_in[9];  f1b = (const float*)d_in[10];
    f2w = (const float*)d_in[11]; f2b = (const float*)d_in[12];
    f3w = (const float*)d_in[13]; f3b = (const float*)d_in[14];
  } else if (n_in >= 15 && in_sizes[3] == 65536 && in_sizes[4] == 256) {
    gw0 = (const float*)d_in[3]; gb0 = (const float*)d_in[4];
    gw1 = (const float*)d_in[5]; gb1 = (const float*)d_in[6];
    gw2 = (const float*)d_in[7]; gb2 = (const float*)d_in[8];
    f1w = (const float*)d_in[9];  f1b = (const float*)d_in[10];
    f2w = (const float*)d_in[11]; f2b = (const float*)d_in[12];
    f3w = (const float*)d_in[13]; f3b = (const float*)d_in[14];
  } else {
    const float* gws = (const float*)d_in[3];
    const float* gbs = (const float*)d_in[4];
    gw0 = gws;          gw1 = gws + 65536;  gw2 = gws + 131072;
    gb0 = gbs;          gb1 = gbs + 256;    gb2 = gbs + 512;
    f1w = (const float*)d_in[5];  f1b = (const float*)d_in[6];
    f2w = (const float*)d_in[7];  f2b = (const float*)d_in[8];
    f3w = (const float*)d_in[9];  f3b = (const float*)d_in[10];
  }

  char* ws = (char*)d_ws;
  float*          c1       = (float*)(ws);                     // 1KB
  unsigned short* W1uR     = (unsigned short*)(ws + 1024);     // 128KB
  unsigned short* W1vR     = (unsigned short*)(ws + 132096);   // 128KB
  unsigned short* W2R      = (unsigned short*)(ws + 263168);   // 128KB
  unsigned short* W3R      = (unsigned short*)(ws + 394240);   // 128KB
  unsigned short* U1       = (unsigned short*)(ws + 525312);   // 1MB (bf16)
  float*          V1c      = (float*)(ws + 1573888);           // 2MB
  float*          partials = (float*)(ws + 3671040);           // 2MB
  const size_t need = 5768192;
  (void)out_size; (void)n_in;

  if (ws_size < need) {
    k_zero<<<dim3((out_size + 255) / 256), dim3(256), 0, stream>>>((float*)d_out, out_size);
    return;
  }

  k_prep<<<dim3(321), dim3(256), 0, stream>>>(edge_w, edge_b, gw0, gb0, gw1, gw2,
                                              W1uR, W1vR, c1, W2R, W3R);
  k_uv<<<dim3(128), dim3(256), 0, stream>>>(x, W1uR, W1vR, c1, U1, V1c);
  k_main<<<dim3(1024), dim3(256), 0, stream>>>(U1, V1c, W2R, W3R, gb1, gb2, partials);
  k_fmlp<<<dim3(32), dim3(256), 0, stream>>>(partials, f1w, f1b, f2w, f2b, f3w, f3b,
                                             (float*)d_out);
}